// Round 13
// baseline (208.854 us; speedup 1.0000x reference)
//
#include <hip/hip_runtime.h>
#include <hip/hip_bf16.h>

typedef __bf16 bf16x8 __attribute__((ext_vector_type(8)));
typedef __bf16 bf16x4 __attribute__((ext_vector_type(4)));
typedef float  f32x4  __attribute__((ext_vector_type(4)));

__device__ __forceinline__ void gload16(const void* g, void* l)
{
    __builtin_amdgcn_global_load_lds((const __attribute__((address_space(1))) void*)g,
                                     (__attribute__((address_space(3))) void*)l, 16, 0, 0);
}

// ---------------- weight pack (generic, prep-only: g1/d1/m1 sections) -------
struct PackArgs {
    const float* src[11];
    __bf16* dst[11];
    int Cout[11], Cin[11], KHW[11], KW[11], Cinpad[11], Kpad[11], mode[11];
    int cum[12];
};

__device__ void pack_dev(const PackArgs& pa, int gidx)
{
    if (gidx >= pa.cum[11]) return;
    int s = 0;
    for (int i = 1; i <= 10; ++i) s += (gidx >= pa.cum[i]) ? 1 : 0;
    int l = gidx - pa.cum[s];
    int Kp = pa.Kpad[s];
    int co = l / Kp, k = l - co * Kp;
    float v = 0.f;
    if (co < pa.Cout[s]) {
        if (pa.mode[s] == 0) {
            int cip = pa.Cinpad[s];
            int tap = k / cip, ci = k - tap * cip;
            if (tap < pa.KHW[s] && ci < pa.Cin[s])
                v = pa.src[s][((long)co * pa.Cin[s] + ci) * pa.KHW[s] + tap];
        } else if (pa.mode[s] == 1) {
            int pix = k >> 7, c = k & 127;
            v = pa.src[s][(long)co * 2048 + c * 16 + pix];
        } else if (pa.mode[s] == 2) {
            v = pa.src[s][(long)co * Kp + k];
        } else {  // mode 3: d1
            int kh = k >> 4, r = k & 15, kw = r >> 1, ci = r & 1;
            if (kh < 7 && kw < 7)
                v = pa.src[s][((long)(co * 2 + ci) * 7 + kh) * 7 + kw];
        }
    }
    pa.dst[s][l] = (__bf16)v;
}

// ---------------- specialized bulk packers (branch1 tail, 8 elems/thread) ---
struct BulkPack { const float* s[8]; __bf16* d[8]; };

template<int CO, int CIN, int KP>
__device__ __forceinline__ void pack_conv8(const float* __restrict__ src,
                                           __bf16* __restrict__ dst, int eb)
{
    int e = eb * 8;
    int co = e / KP;
    int k  = e - co * KP;
    int tap = k / CIN;
    int ci  = k - tap * CIN;
    bf16x8 o = {};
    if (co < CO && tap < 9) {
        const float* s = src + ((long)co * CIN + ci) * 9 + tap;
#pragma unroll
        for (int j = 0; j < 8; ++j) o[j] = (__bf16)s[j * 9];
    }
    *(bf16x8*)&dst[e] = o;
}

__device__ __forceinline__ void pack_fc1_8(const float* __restrict__ src,
                                           __bf16* __restrict__ dst, int eb)
{
    int e = eb * 8;
    int co = e >> 11, k = e & 2047;
    int pix = k >> 7, c = k & 127;
    const float* s = src + (long)co * 2048 + c * 16 + pix;
    bf16x8 o;
#pragma unroll
    for (int j = 0; j < 8; ++j) o[j] = (__bf16)s[j * 16];
    *(bf16x8*)&dst[e] = o;
}

__device__ __forceinline__ void pack_fc2_8(const float* __restrict__ src,
                                           __bf16* __restrict__ dst, int eb)
{
    int e = eb * 8;
    f32x4 lo = *(const f32x4*)&src[e];
    f32x4 hi = *(const f32x4*)&src[e + 4];
    bf16x8 o = { (__bf16)lo.x, (__bf16)lo.y, (__bf16)lo.z, (__bf16)lo.w,
                 (__bf16)hi.x, (__bf16)hi.y, (__bf16)hi.z, (__bf16)hi.w };
    *(bf16x8*)&dst[e] = o;
}

// ---------------- NCHW f32 (C<=8) -> NHWC8 bf16, vectorized (pixel/thread) --
__device__ void pad_nhwc8v_dev(const float* __restrict__ in, __bf16* __restrict__ out,
                               int C, int log2HW, int pidx)
{
    int b = pidx >> log2HW;
    int pix = pidx & ((1 << log2HW) - 1);
    const float* s = in + (((long)b * C) << log2HW) + pix;
    bf16x8 o = {};
    for (int c = 0; c < C; ++c) o[c] = (__bf16)s[(long)c << log2HW];
    *(bf16x8*)&out[(long)pidx * 8] = o;
}

// ---------------- dflow NCHW [64,2,32,32] -> padded NHWC [64,40,40,2] -------
__device__ void pad_dflow_dev(const float* __restrict__ in, __bf16* __restrict__ out, int idx)
{
    if (idx >= 64 * 40 * 40 * 2) return;
    int c = idx & 1;
    int t = idx >> 1;
    int x = t % 40;
    int t2 = t / 40;
    int y = t2 % 40;
    int b = t2 / 40;
    int hi = y - 3, wi = x - 3;
    float v = 0.f;
    if ((unsigned)hi < 32u && (unsigned)wi < 32u)
        v = in[((long)(b * 2 + c) * 32 + hi) * 32 + wi];
    out[idx] = (__bf16)v;
}

// ---------------- hidden NCHW f32 -> enc NHWC bf16 channels 0..127 ----------
__device__ void hid_dev(char* smem, const float* __restrict__ h,
                        __bf16* __restrict__ enc, int blk, int tid)
{
    auto t = reinterpret_cast<float (*)[65]>(smem);
    int b = blk >> 6;
    int inner = blk & 63;
    int ct = inner & 3, pt = inner >> 2;
    int c0 = ct * 32, p0 = pt * 64;
    int cl = tid >> 6, pl = tid & 63;
#pragma unroll
    for (int i = 0; i < 8; ++i)
        t[cl + i * 4][pl] = h[((long)(b * 128 + c0 + cl + i * 4)) * 1024 + p0 + pl];
    __syncthreads();
    int cc = tid & 31, p2 = tid >> 5;
#pragma unroll
    for (int i = 0; i < 8; ++i)
        enc[((long)b * 1024 + p0 + p2 + i * 8) * 288 + c0 + cc] = (__bf16)t[cc][p2 + i * 8];
}

// ---------------- prep: b1 weight packs + vectorized pads + zeroing ---------
// ZERO section covers fc1acc (256KB) + fc2acc (64KB) + zpad (4KB, contiguous).
#define PACK_B 144
#define GEOV_B 1024
#define DF_B 800
#define MASKV_B 256
#define ZERO_B 81
// total 2,305
__global__ __launch_bounds__(256) void prep_kern(PackArgs pa,
    const float* __restrict__ geo, __bf16* __restrict__ geo_p,
    const float* __restrict__ dflow, __bf16* __restrict__ dflow_pp,
    const float* __restrict__ mask, __bf16* __restrict__ mask_p,
    float* __restrict__ fc1acc, float* __restrict__ fc2acc)
{
    int blk = blockIdx.x, tid = threadIdx.x;
    if (blk < PACK_B) { pack_dev(pa, blk * 256 + tid); return; }
    blk -= PACK_B;
    if (blk < GEOV_B) { pad_nhwc8v_dev(geo, geo_p, 8, 12, blk * 256 + tid); return; }
    blk -= GEOV_B;
    if (blk < DF_B) { pad_dflow_dev(dflow, dflow_pp, blk * 256 + tid); return; }
    blk -= DF_B;
    if (blk < MASKV_B) { pad_nhwc8v_dev(mask, mask_p, 1, 10, blk * 256 + tid); return; }
    blk -= MASKV_B;
    long zi = (long)blk * 256 + tid;
    f32x4 z = {};
    if (zi < 16384) *(f32x4*)&fc1acc[zi * 4] = z;            // 64x1024 f32
    else { zi -= 16384; *(f32x4*)&fc2acc[zi * 4] = z; }      // 64x256 f32 + 4KB zpad
}

// ---------------- implicit-GEMM conv, NHWC, reg-prefetch --------------------
struct ConvGeom {
    int CinTot;
    int Hin, Win;
    int log2HWout, log2Wout;
    int stride, pad;
    int Kpad;                   // multiple of BK
    int KHW;
    int Cout, CTOT, C0;
    int b0i, b0o;
};

// ======== conv_dev3: branch2-specialized (BM=64, BN=128, BK=64, 256 thr) ====
// global_load_lds staging (linear LDS, source-pre-swizzled st-16x16 XOR) +
// swizzled ds_read. Boundary lanes read a zero page. Requires Kpad == 9*CINPAD
// (no zero-pad taps) and 16B-aligned rows (Kpad*2 % 16 == 0).
template<int CINPAD>
__device__ __forceinline__ void conv_dev3(char* __restrict__ smem_, int bx,
    const __bf16* __restrict__ in_, const __bf16* __restrict__ A,
    const float* __restrict__ bias, __bf16* __restrict__ out_,
    const ConvGeom& g, const __bf16* __restrict__ zpad)
{
    constexpr int BM = 64, BN = 128, BK = 64;
    constexpr int ABYTES = BM * BK * 2;   // 8192
    const int tid = threadIdx.x;
    const int w4 = tid >> 6, l = tid & 63;
    const int lane = l;
    const int wn = w4 * 32;               // WMW=1 (wm=0), WNW=4
    const int lr = lane & 15, lk = (lane >> 4) * 8;
    const int ntile = bx * BN;

    // A staging lane constants: LDS byte X -> (row, data col) with XOR swizzle
    int rowA[2], colA[2];
#pragma unroll
    for (int j = 0; j < 2; ++j) {
        int X = ((w4 * 2 + j) << 10) + l * 16;
        rowA[j] = X >> 7;
        int cb = (X & 127) ^ ((rowA[j] & 7) << 4);
        colA[j] = cb >> 1;
    }
    // B staging lane constants
    int rowB[4], colB[4], hi0a[4], wi0a[4];
    long nbase[4];
#pragma unroll
    for (int j = 0; j < 4; ++j) {
        int X = ((w4 * 4 + j) << 10) + l * 16;
        rowB[j] = X >> 7;
        int cb = (X & 127) ^ ((rowB[j] & 7) << 4);
        colB[j] = cb >> 1;
        int n = ntile + rowB[j];
        int bb = g.b0i + (n >> g.log2HWout);
        int pix = n & ((1 << g.log2HWout) - 1);
        int ho = pix >> g.log2Wout, wo = pix & ((1 << g.log2Wout) - 1);
        hi0a[j] = ho * g.stride - g.pad;
        wi0a[j] = wo * g.stride - g.pad;
        nbase[j] = (((long)bb * g.Hin + hi0a[j]) * g.Win + wi0a[j]) * g.CinTot;
    }

    f32x4 acc[4][2] = {};
    for (int k0 = 0; k0 < g.Kpad; k0 += BK) {
        if (k0) __syncthreads();
        // ---- stage A (2 x 1KB DMA per wave-quarter) ----
#pragma unroll
        for (int j = 0; j < 2; ++j) {
            const __bf16* ga = A + (long)rowA[j] * g.Kpad + k0 + colA[j];
            gload16(ga, smem_ + ((w4 * 2 + j) << 10));
        }
        // ---- stage B (tap is uniform per K-step since BK | CINPAD) ----
        int tap = k0 / CINPAD;
        int ci0 = k0 % CINPAD;
        int kh = tap / 3, kw = tap - kh * 3;
        int toff = (kh * g.Win + kw) * g.CinTot + ci0;
#pragma unroll
        for (int j = 0; j < 4; ++j) {
            int hi = hi0a[j] + kh, wi = wi0a[j] + kw;
            bool v = (unsigned)hi < (unsigned)g.Hin && (unsigned)wi < (unsigned)g.Win;
            const __bf16* gb = v ? (in_ + nbase[j] + toff + colB[j]) : (zpad + l * 8);
            gload16(gb, smem_ + ABYTES + ((w4 * 4 + j) << 10));
        }
        __syncthreads();   // compiler drains vmcnt before barrier
        // ---- compute (swizzled ds_read_b128, conflict-free) ----
#pragma unroll
        for (int kk = 0; kk < BK; kk += 32) {
            bf16x8 bfr[2], afr[4];
#pragma unroll
            for (int jn = 0; jn < 2; ++jn) {
                int row = wn + jn * 16 + lr;
                int byte = ABYTES + row * 128 + (((kk + lk) * 2) ^ ((row & 7) << 4));
                bfr[jn] = *(const bf16x8*)(smem_ + byte);
            }
#pragma unroll
            for (int i = 0; i < 4; ++i) {
                int row = i * 16 + lr;
                int byte = row * 128 + (((kk + lk) * 2) ^ ((row & 7) << 4));
                afr[i] = *(const bf16x8*)(smem_ + byte);
            }
#pragma unroll
            for (int i = 0; i < 4; ++i) {
                acc[i][0] = __builtin_amdgcn_mfma_f32_16x16x32_bf16(afr[i], bfr[0], acc[i][0], 0, 0, 0);
                acc[i][1] = __builtin_amdgcn_mfma_f32_16x16x32_bf16(afr[i], bfr[1], acc[i][1], 0, 0, 0);
            }
        }
    }

    const int HWm1 = (1 << g.log2HWout) - 1;
#pragma unroll
    for (int i = 0; i < 4; ++i) {
        int co = i * 16 + (lane >> 4) * 4;
        if (co >= g.Cout) continue;
        f32x4 bv4 = *(const f32x4*)&bias[co];
#pragma unroll
        for (int jn = 0; jn < 2; ++jn) {
            int nn = ntile + wn + jn * 16 + lr;
            f32x4 v = acc[i][jn] + bv4;
            v.x = fmaxf(v.x, 0.f); v.y = fmaxf(v.y, 0.f);
            v.z = fmaxf(v.z, 0.f); v.w = fmaxf(v.w, 0.f);
            int ob = nn >> g.log2HWout, opix = nn & HWm1;
            long o = (((long)(g.b0o + ob) << g.log2HWout) + opix) * g.CTOT + g.C0 + co;
            bf16x4 o4 = { (__bf16)v.x, (__bf16)v.y, (__bf16)v.z, (__bf16)v.w };
            *(bf16x4*)&out_[o] = o4;
        }
    }
}

// ======== conv_dev2: generalized wave tiling (c1 + c2f/c3f host) ============
template<int BM, int BN, int BK, int THREADS, int WMW, int WNW, int CINPAD, int KW, int MODE, bool OUTBF, bool RELU>
__device__ __forceinline__ void conv_dev2(char* __restrict__ smem_, int bx,
    const __bf16* __restrict__ in_, const __bf16* __restrict__ A,
    const float* __restrict__ bias, void* __restrict__ out_, const ConvGeom& g)
{
    constexpr int MEXT = BM / WMW;
    constexpr int NEXT = BN / WNW;
    constexpr int MFRAG = MEXT / 16;
    constexpr int NFRAG = NEXT / 16;
    constexpr int KROW = BK / 8;
    constexpr int SROWS = THREADS / KROW;
    constexpr int APASS = BM / SROWS;
    constexpr int BPASS = BN / SROWS;
    constexpr int LDK = BK + 8;

    auto As = reinterpret_cast<__bf16 (*)[LDK]>(smem_);
    auto Bs = reinterpret_cast<__bf16 (*)[LDK]>(smem_ + (size_t)BM * LDK * sizeof(__bf16));

    const int tid = threadIdx.x;
    const int ntile = bx * BN;
    const int lane = tid & 63, w = tid >> 6;
    const int wm = (w / WNW) * MEXT, wn = (w % WNW) * NEXT;
    const int lr = lane & 15, lk = (lane >> 4) * 8;
    const int srow = tid / KROW, scol = (tid % KROW) * 8;

    long nbase[BPASS]; int hi0a[BPASS], wi0a[BPASS];
#pragma unroll
    for (int j = 0; j < BPASS; ++j) {
        int n = ntile + j * SROWS + srow;
        int bb = g.b0i + (n >> g.log2HWout);
        int pix = n & ((1 << g.log2HWout) - 1);
        int ho = pix >> g.log2Wout, wo = pix & ((1 << g.log2Wout) - 1);
        hi0a[j] = ho * g.stride - g.pad;
        wi0a[j] = wo * g.stride - g.pad;
        nbase[j] = (((long)bb * g.Hin + hi0a[j]) * g.Win + wi0a[j]) * g.CinTot;
    }

    bf16x8 av[APASS], bv[BPASS];
    auto LOAD = [&](int k0) {
        int k = k0 + scol;
#pragma unroll
        for (int ja = 0; ja < APASS; ++ja)
            av[ja] = *(const bf16x8*)&A[(long)(ja * SROWS + srow) * g.Kpad + k];
        if (MODE == 1) {
            int q = k >> 3;
            int off = (q >> 1) * (g.Win * g.CinTot) + (q & 1) * 8;
#pragma unroll
            for (int j = 0; j < BPASS; ++j)
                bv[j] = *(const bf16x8*)&in_[nbase[j] + off];
        } else {
            int tap = k / CINPAD;
            int ci  = k - tap * CINPAD;
            int kh  = tap / KW;
            int kw  = tap - kh * KW;
            bool tv = tap < g.KHW;
            int off = (kh * g.Win + kw) * g.CinTot + ci;
#pragma unroll
            for (int j = 0; j < BPASS; ++j) {
                bf16x8 z = {};
                int hi = hi0a[j] + kh, wi = wi0a[j] + kw;
                if (tv && (unsigned)hi < (unsigned)g.Hin && (unsigned)wi < (unsigned)g.Win)
                    z = *(const bf16x8*)&in_[nbase[j] + off];
                bv[j] = z;
            }
        }
    };

    f32x4 acc[MFRAG][NFRAG] = {};
    LOAD(0);
    for (int k0 = 0;;) {
        if (k0) __syncthreads();
#pragma unroll
        for (int ja = 0; ja < APASS; ++ja)
            *(bf16x8*)&As[ja * SROWS + srow][scol] = av[ja];
#pragma unroll
        for (int j = 0; j < BPASS; ++j)
            *(bf16x8*)&Bs[j * SROWS + srow][scol] = bv[j];
        __syncthreads();
        int kn = k0 + BK;
        bool more = kn < g.Kpad;
        if (more) LOAD(kn);
#pragma unroll
        for (int kk = 0; kk < BK; kk += 32) {
            bf16x8 bfr[NFRAG], afr[MFRAG];
#pragma unroll
            for (int jn = 0; jn < NFRAG; ++jn)
                bfr[jn] = *(const bf16x8*)&Bs[wn + jn * 16 + lr][kk + lk];
#pragma unroll
            for (int i = 0; i < MFRAG; ++i)
                afr[i] = *(const bf16x8*)&As[wm + i * 16 + lr][kk + lk];
#pragma unroll
            for (int i = 0; i < MFRAG; ++i)
#pragma unroll
                for (int jn = 0; jn < NFRAG; ++jn)
                    acc[i][jn] = __builtin_amdgcn_mfma_f32_16x16x32_bf16(afr[i], bfr[jn], acc[i][jn], 0, 0, 0);
        }
        if (!more) break;
        k0 = kn;
    }

    const int HWm1 = (1 << g.log2HWout) - 1;
#pragma unroll
    for (int i = 0; i < MFRAG; ++i) {
        int co = wm + i * 16 + (lane >> 4) * 4;
        if (co >= g.Cout) continue;
        f32x4 bv4 = *(const f32x4*)&bias[co];
#pragma unroll
        for (int jn = 0; jn < NFRAG; ++jn) {
            int nn = ntile + wn + jn * 16 + lr;
            f32x4 v = acc[i][jn] + bv4;
            if (RELU) { v.x = fmaxf(v.x, 0.f); v.y = fmaxf(v.y, 0.f); v.z = fmaxf(v.z, 0.f); v.w = fmaxf(v.w, 0.f); }
            int ob = nn >> g.log2HWout, opix = nn & HWm1;
            long o = (((long)(g.b0o + ob) << g.log2HWout) + opix) * g.CTOT + g.C0 + co;
            if (OUTBF) {
                bf16x4 o4 = { (__bf16)v.x, (__bf16)v.y, (__bf16)v.z, (__bf16)v.w };
                *(bf16x4*)&((__bf16*)out_)[o] = o4;
            } else {
                *(f32x4*)&((float*)out_)[o] = v;
            }
        }
    }
}

// ======== legacy conv_dev (branch1 short-K convs) ===========================
template<int BM, int BN, int BK, int THREADS, int CINPAD, int KW, int MODE, bool OUTBF, bool RELU>
__device__ __forceinline__ void conv_dev(char* __restrict__ smem_, int bx,
    const __bf16* __restrict__ in_, const __bf16* __restrict__ A,
    const float* __restrict__ bias, void* __restrict__ out_, const ConvGeom& g)
{
    constexpr int WAVES = THREADS / 64;
    constexpr int WN = BN / 32;
    constexpr int WM = WAVES / WN;
    constexpr int MEXT = BM / WM;
    constexpr int MFRAG = MEXT / 16;
    constexpr int KROW = BK / 8;
    constexpr int SROWS = THREADS / KROW;
    constexpr int APASS = BM / SROWS;
    constexpr int BPASS = BN / SROWS;

    auto As = reinterpret_cast<__bf16 (*)[BK + 8]>(smem_);
    auto Bs = reinterpret_cast<__bf16 (*)[BK + 8]>(smem_ + (size_t)BM * (BK + 8) * sizeof(__bf16));

    const int tid = threadIdx.x;
    const int ntile = bx * BN;
    const int lane = tid & 63, w = tid >> 6;
    const int wm = (w / WN) * MEXT, wn = (w % WN) * 32;
    const int lr = lane & 15, lk = (lane >> 4) * 8;
    const int srow = tid / KROW, scol = (tid % KROW) * 8;

    long nbase[BPASS]; int hi0a[BPASS], wi0a[BPASS];
#pragma unroll
    for (int j = 0; j < BPASS; ++j) {
        int n = ntile + j * SROWS + srow;
        int bb = g.b0i + (n >> g.log2HWout);
        int pix = n & ((1 << g.log2HWout) - 1);
        int ho = pix >> g.log2Wout, wo = pix & ((1 << g.log2Wout) - 1);
        hi0a[j] = ho * g.stride - g.pad;
        wi0a[j] = wo * g.stride - g.pad;
        nbase[j] = (((long)bb * g.Hin + hi0a[j]) * g.Win + wi0a[j]) * g.CinTot;
    }

    bf16x8 av[APASS], bv[BPASS];
    auto LOAD = [&](int k0) {
        int k = k0 + scol;
#pragma unroll
        for (int ja = 0; ja < APASS; ++ja)
            av[ja] = *(const bf16x8*)&A[(long)(ja * SROWS + srow) * g.Kpad + k];
        if (MODE == 1) {
            int q = k >> 3;
            int off = (q >> 1) * (g.Win * g.CinTot) + (q & 1) * 8;
#pragma unroll
            for (int j = 0; j < BPASS; ++j)
                bv[j] = *(const bf16x8*)&in_[nbase[j] + off];
        } else {
            int tap = k / CINPAD;
            int ci  = k - tap * CINPAD;
            int kh  = tap / KW;
            int kw  = tap - kh * KW;
            bool tv = tap < g.KHW;
            int off = (kh * g.Win + kw) * g.CinTot + ci;
#pragma unroll
            for (int j = 0; j < BPASS; ++j) {
                bf16x8 z = {};
                int hi = hi0a[j] + kh, wi = wi0a[j] + kw;
                if (tv && (unsigned)hi < (unsigned)g.Hin && (unsigned)wi < (unsigned)g.Win)
                    z = *(const bf16x8*)&in_[nbase[j] + off];
                bv[j] = z;
            }
        }
    };

    f32x4 acc[MFRAG][2] = {};
    LOAD(0);
    for (int k0 = 0;;) {
        if (k0) __syncthreads();
#pragma unroll
        for (int ja = 0; ja < APASS; ++ja)
            *(bf16x8*)&As[ja * SROWS + srow][scol] = av[ja];
#pragma unroll
        for (int j = 0; j < BPASS; ++j)
            *(bf16x8*)&Bs[j * SROWS + srow][scol] = bv[j];
        __syncthreads();
        int kn = k0 + BK;
        bool more = kn < g.Kpad;
        if (more) LOAD(kn);
#pragma unroll
        for (int kk = 0; kk < BK; kk += 32) {
            bf16x8 bfr[2];
            bfr[0] = *(const bf16x8*)&Bs[wn + lr][kk + lk];
            bfr[1] = *(const bf16x8*)&Bs[wn + 16 + lr][kk + lk];
#pragma unroll
            for (int i = 0; i < MFRAG; ++i) {
                bf16x8 a = *(const bf16x8*)&As[wm + i * 16 + lr][kk + lk];
                acc[i][0] = __builtin_amdgcn_mfma_f32_16x16x32_bf16(a, bfr[0], acc[i][0], 0, 0, 0);
                acc[i][1] = __builtin_amdgcn_mfma_f32_16x16x32_bf16(a, bfr[1], acc[i][1], 0, 0, 0);
            }
        }
        if (!more) break;
        k0 = kn;
    }

    const int HWm1 = (1 << g.log2HWout) - 1;
#pragma unroll
    for (int i = 0; i < MFRAG; ++i) {
        int co = wm + i * 16 + (lane >> 4) * 4;
        if (co >= g.Cout) continue;
        f32x4 bv4 = *(const f32x4*)&bias[co];
#pragma unroll
        for (int jb = 0; jb < 2; ++jb) {
            int nn = ntile + wn + jb * 16 + lr;
            f32x4 v = acc[i][jb] + bv4;
            if (RELU) { v.x = fmaxf(v.x, 0.f); v.y = fmaxf(v.y, 0.f); v.z = fmaxf(v.z, 0.f); v.w = fmaxf(v.w, 0.f); }
            int ob = nn >> g.log2HWout, opix = nn & HWm1;
            long o = (((long)(g.b0o + ob) << g.log2HWout) + opix) * g.CTOT + g.C0 + co;
            if (OUTBF) {
                bf16x4 o4 = { (__bf16)v.x, (__bf16)v.y, (__bf16)v.z, (__bf16)v.w };
                *(bf16x4*)&((__bf16*)out_)[o] = o4;
            } else {
                *(f32x4*)&((float*)out_)[o] = v;
            }
        }
    }
}

// ---- standalone conv with M-split grid (c1): grid = (ntiles, mtiles) --------
template<int BM, int BN, int BK, int THREADS, int WMW, int WNW, int CINPAD, int KW, int MODE, bool OUTBF, bool RELU>
__global__ __launch_bounds__(THREADS) void conv_gemm2(
    const __bf16* __restrict__ in_, const __bf16* __restrict__ A,
    const float* __restrict__ bias, void* __restrict__ out_, ConvGeom g)
{
    __shared__ __attribute__((aligned(16))) char smem[(BM + BN) * (BK + 8) * 2];
    int mt = blockIdx.y * BM;
    ConvGeom gg = g;
    gg.C0 += mt;
    gg.Cout -= mt;
    conv_dev2<BM, BN, BK, THREADS, WMW, WNW, CINPAD, KW, MODE, OUTBF, RELU>(
        smem, blockIdx.x, in_, A + (long)mt * g.Kpad, bias + mt, out_, gg);
}

// ======== conv + fused GroupNorm(cpg=4) + relu (c2/c3) ======================
template<int BM, int BN, int BK, int THREADS, int WMW, int WNW, int CINPAD, int KW, int PPB>
__global__ __launch_bounds__(THREADS) void conv_gn_kern(
    const __bf16* __restrict__ in_, const __bf16* __restrict__ A,
    const float* __restrict__ bias, const float* __restrict__ gns,
    const float* __restrict__ gnb, __bf16* __restrict__ out_, ConvGeom g)
{
    constexpr int MEXT = BM / WMW;
    constexpr int NEXT = BN / WNW;
    constexpr int MFRAG = MEXT / 16;
    constexpr int NFRAG = NEXT / 16;
    constexpr int KROW = BK / 8;
    constexpr int SROWS = THREADS / KROW;
    constexpr int APASS = BM / SROWS;
    constexpr int BPASS = BN / SROWS;
    constexpr int LDK = BK + 8;

    __shared__ __attribute__((aligned(16))) char smem_[(BM + BN) * (BK + 8) * 2];
    auto As = reinterpret_cast<__bf16 (*)[LDK]>(smem_);
    auto Bs = reinterpret_cast<__bf16 (*)[LDK]>(smem_ + (size_t)BM * LDK * sizeof(__bf16));
    static_assert((size_t)BN * (BM + 4) * 4 <= (size_t)(BM + BN) * (BK + 8) * 2, "smf fits");

    const int tid = threadIdx.x;
    const int mt = blockIdx.y * BM;
    const __bf16* Ap = A + (long)mt * g.Kpad;
    const int C0 = g.C0 + mt;
    const int ntile = blockIdx.x * BN;
    const int lane = tid & 63, w = tid >> 6;
    const int wm = (w / WNW) * MEXT, wn = (w % WNW) * NEXT;
    const int lr = lane & 15, lk = (lane >> 4) * 8;
    const int srow = tid / KROW, scol = (tid % KROW) * 8;

    long nbase[BPASS]; int hi0a[BPASS], wi0a[BPASS];
#pragma unroll
    for (int j = 0; j < BPASS; ++j) {
        int n = ntile + j * SROWS + srow;
        int bb = g.b0i + (n >> g.log2HWout);
        int pix = n & ((1 << g.log2HWout) - 1);
        int ho = pix >> g.log2Wout, wo = pix & ((1 << g.log2Wout) - 1);
        hi0a[j] = ho * g.stride - g.pad;
        wi0a[j] = wo * g.stride - g.pad;
        nbase[j] = (((long)bb * g.Hin + hi0a[j]) * g.Win + wi0a[j]) * g.CinTot;
    }

    bf16x8 av[APASS], bv[BPASS];
    auto LOAD = [&](int k0) {
        int k = k0 + scol;
#pragma unroll
        for (int ja = 0; ja < APASS; ++ja)
            av[ja] = *(const bf16x8*)&Ap[(long)(ja * SROWS + srow) * g.Kpad + k];
        int tap = k / CINPAD;
        int ci  = k - tap * CINPAD;
        int kh  = tap / KW;
        int kw  = tap - kh * KW;
        bool tv = tap < g.KHW;
        int off = (kh * g.Win + kw) * g.CinTot + ci;
#pragma unroll
        for (int j = 0; j < BPASS; ++j) {
            bf16x8 z = {};
            int hi = hi0a[j] + kh, wi = wi0a[j] + kw;
            if (tv && (unsigned)hi < (unsigned)g.Hin && (unsigned)wi < (unsigned)g.Win)
                z = *(const bf16x8*)&in_[nbase[j] + off];
            bv[j] = z;
        }
    };

    f32x4 acc[MFRAG][NFRAG] = {};
    LOAD(0);
    for (int k0 = 0;;) {
        if (k0) __syncthreads();
#pragma unroll
        for (int ja = 0; ja < APASS; ++ja)
            *(bf16x8*)&As[ja * SROWS + srow][scol] = av[ja];
#pragma unroll
        for (int j = 0; j < BPASS; ++j)
            *(bf16x8*)&Bs[j * SROWS + srow][scol] = bv[j];
        __syncthreads();
        int kn = k0 + BK;
        bool more = kn < g.Kpad;
        if (more) LOAD(kn);
#pragma unroll
        for (int kk = 0; kk < BK; kk += 32) {
            bf16x8 bfr[NFRAG], afr[MFRAG];
#pragma unroll
            for (int jn = 0; jn < NFRAG; ++jn)
                bfr[jn] = *(const bf16x8*)&Bs[wn + jn * 16 + lr][kk + lk];
#pragma unroll
            for (int i = 0; i < MFRAG; ++i)
                afr[i] = *(const bf16x8*)&As[wm + i * 16 + lr][kk + lk];
#pragma unroll
            for (int i = 0; i < MFRAG; ++i)
#pragma unroll
                for (int jn = 0; jn < NFRAG; ++jn)
                    acc[i][jn] = __builtin_amdgcn_mfma_f32_16x16x32_bf16(afr[i], bfr[jn], acc[i][jn], 0, 0, 0);
        }
        if (!more) break;
        k0 = kn;
    }

    // ---- fused GN epilogue ----
    __syncthreads();
    auto smf = reinterpret_cast<float (*)[BM + 4]>(smem_);
#pragma unroll
    for (int i = 0; i < MFRAG; ++i) {
        int m = wm + i * 16 + (lane >> 4) * 4;
        f32x4 bv4 = *(const f32x4*)&bias[C0 + m];
#pragma unroll
        for (int jn = 0; jn < NFRAG; ++jn) {
            int n = wn + jn * 16 + lr;
            *(f32x4*)&smf[n][m] = acc[i][jn] + bv4;
        }
    }
    __syncthreads();

    constexpr int NSETS = (BN / PPB) * (BM / 4);
    constexpr int TPS = THREADS / NSETS;
    constexpr int PPT = PPB / TPS;
    const int set = tid / TPS, part = tid % TPS;
    const int bit = set / (BM / 4);
    const int grp = set % (BM / 4);
    const int m0 = grp * 4;
    float sum = 0.f, sq = 0.f;
#pragma unroll
    for (int p = 0; p < PPT; ++p) {
        int nl = bit * PPB + part + p * TPS;
        f32x4 v = *(const f32x4*)&smf[nl][m0];
        sum += v.x + v.y + v.z + v.w;
        sq  += v.x * v.x + v.y * v.y + v.z * v.z + v.w * v.w;
    }
#pragma unroll
    for (int off = TPS >> 1; off > 0; off >>= 1) {
        sum += __shfl_xor(sum, off);
        sq  += __shfl_xor(sq, off);
    }
    const float len = (float)(PPB * 4);
    float mean = sum / len;
    float var  = sq / len - mean * mean;
    float rstd = rsqrtf(fmaxf(var, 0.f) + 1e-5f);
    f32x4 s4 = *(const f32x4*)&gns[C0 + m0];
    f32x4 b4 = *(const f32x4*)&gnb[C0 + m0];
    const int HWm1 = (1 << g.log2HWout) - 1;
#pragma unroll
    for (int p = 0; p < PPT; ++p) {
        int nl = bit * PPB + part + p * TPS;
        f32x4 v = *(const f32x4*)&smf[nl][m0];
        f32x4 r;
        r.x = fmaxf((v.x - mean) * rstd * s4.x + b4.x, 0.f);
        r.y = fmaxf((v.y - mean) * rstd * s4.y + b4.y, 0.f);
        r.z = fmaxf((v.z - mean) * rstd * s4.z + b4.z, 0.f);
        r.w = fmaxf((v.w - mean) * rstd * s4.w + b4.w, 0.f);
        int n = ntile + nl;
        int ob = n >> g.log2HWout, opix = n & HWm1;
        long o = (((long)(g.b0o + ob) << g.log2HWout) + opix) * g.CTOT + C0 + m0;
        bf16x4 o4 = { (__bf16)r.x, (__bf16)r.y, (__bf16)r.z, (__bf16)r.w };
        *(bf16x4*)&out_[o] = o4;
    }
}

// ---------------- fat branch 1: g1 + d1 + m1 + specialized bulk pack ---------
#define B1_CONV 3072
#define B1_PACK 775
__global__ __launch_bounds__(512) void branch1_kern(
    const __bf16* __restrict__ geo_p, const __bf16* __restrict__ wg1, const float* __restrict__ g1_b, __bf16* __restrict__ g1out,
    const __bf16* __restrict__ dflow_pp, const __bf16* __restrict__ wd1, const float* __restrict__ d1_b, __bf16* __restrict__ d1out,
    const __bf16* __restrict__ mask_p, const __bf16* __restrict__ wm1, const float* __restrict__ m1_b, __bf16* __restrict__ m1out,
    BulkPack bp, ConvGeom gg1, ConvGeom gd1, ConvGeom gm1)
{
    __shared__ __attribute__((aligned(16))) char smem[27648];
    int x = blockIdx.x;
    if (x < 2048) {
        conv_dev<128, 128, 32, 512, 8, 3, 0, true, true>(smem, x, geo_p, wg1, g1_b, g1out, gg1);
        return;
    }
    if (x < 2560) {
        conv_dev<128, 128, 32, 512, 8, 7, 1, true, true>(smem, x - 2048, dflow_pp, wd1, d1_b, d1out, gd1);
        return;
    }
    if (x < B1_CONV) {
        conv_dev<64, 128, 64, 512, 8, 3, 0, true, true>(smem, x - 2560, mask_p, wm1, m1_b, m1out, gm1);
        return;
    }
    int x2 = x - B1_CONV;
    int tid = threadIdx.x;
    if (x2 < 18)       pack_conv8<64, 128, 1152>(bp.s[0], bp.d[0], x2 * 512 + tid);
    else if (x2 < 36)  pack_conv8<64, 128, 1152>(bp.s[1], bp.d[1], (x2 - 18) * 512 + tid);
    else if (x2 < 45)  pack_conv8<32, 64, 576>(bp.s[2], bp.d[2], (x2 - 36) * 512 + tid);
    else if (x2 < 127) pack_conv8<128, 288, 2624>(bp.s[3], bp.d[3], (x2 - 45) * 512 + tid);
    else if (x2 < 163) pack_conv8<128, 128, 1152>(bp.s[4], bp.d[4], (x2 - 127) * 512 + tid);
    else if (x2 < 199) pack_conv8<128, 128, 1152>(bp.s[5], bp.d[5], (x2 - 163) * 512 + tid);
    else if (x2 < 711) pack_fc1_8(bp.s[6], bp.d[6], (x2 - 199) * 512 + tid);
    else               pack_fc2_8(bp.s[7], bp.d[7], (x2 - 711) * 512 + tid);
}

// ---------------- fat branch 2: g2 + d2 + m2 (conv_dev3) + hid transpose -----
#define B2_CONV 1536
#define B2_HID 4096
__global__ __launch_bounds__(256) void branch2_kern(
    const __bf16* __restrict__ g1out, const __bf16* __restrict__ wg2, const float* __restrict__ g2_b,
    const __bf16* __restrict__ d1out, const __bf16* __restrict__ wd2, const float* __restrict__ d2_b,
    const __bf16* __restrict__ m1out, const __bf16* __restrict__ wm2, const float* __restrict__ m2_b,
    const float* __restrict__ hidden, __bf16* __restrict__ enc, const __bf16* __restrict__ zpad,
    ConvGeom gg2, ConvGeom gd2, ConvGeom gm2)
{
    __shared__ __attribute__((aligned(16))) char smem[24576];  // A 8KB + B 16KB
    int x = blockIdx.x;
    if (x >= B2_CONV) { hid_dev(smem, hidden, enc, x - B2_CONV, threadIdx.x); return; }
    int sec = x % 3, bx = x / 3;
    if (sec == 0)
        conv_dev3<128>(smem, bx, g1out, wg2, g2_b, enc, gg2, zpad);
    else if (sec == 1)
        conv_dev3<128>(smem, bx, d1out, wd2, d2_b, enc, gd2, zpad);
    else
        conv_dev3<64>(smem, bx, m1out, wm2, m2_b, enc, gm2, zpad);
}

// ---------------- fc1 split-K: grid (4 kchunks, 16 mtiles), atomic f32 ------
__global__ __launch_bounds__(256) void fc1_splitk(
    const __bf16* __restrict__ A, const __bf16* __restrict__ B,
    float* __restrict__ outacc)
{
    __shared__ __attribute__((aligned(16))) __bf16 As[64][40];
    __shared__ __attribute__((aligned(16))) __bf16 Bs[64][40];
    const int tid = threadIdx.x;
    const int mtile = blockIdx.y * 64;
    const int kbase = blockIdx.x * 512;
    const int lane = tid & 63, w = tid >> 6;
    const int wm = (w >> 1) * 32, wn = (w & 1) * 32;
    const int lr = lane & 15, lk = (lane >> 4) * 8;
    const int srow = tid >> 2, soff = (tid & 3) * 8;

    f32x4 acc00 = {}, acc01 = {}, acc10 = {}, acc11 = {};
    for (int k0 = 0; k0 < 512; k0 += 32) {
        *(bf16x8*)&As[srow][soff] = *(const bf16x8*)&A[(long)(mtile + srow) * 2048 + kbase + k0 + soff];
        *(bf16x8*)&Bs[srow][soff] = *(const bf16x8*)&B[(long)srow * 2048 + kbase + k0 + soff];
        __syncthreads();
        bf16x8 a0 = *(const bf16x8*)&As[wm + lr][lk];
        bf16x8 a1 = *(const bf16x8*)&As[wm + 16 + lr][lk];
        bf16x8 b0f = *(const bf16x8*)&Bs[wn + lr][lk];
        bf16x8 b1f = *(const bf16x8*)&Bs[wn + 16 + lr][lk];
        acc00 = __builtin_amdgcn_mfma_f32_16x16x32_bf16(a0, b0f, acc00, 0, 0, 0);
        acc01 = __builtin_amdgcn_mfma_f32_16x16x32_bf16(a0, b1f, acc01, 0, 0, 0);
        acc10 = __builtin_amdgcn_mfma_f32_16x16x32_bf16(a1, b0f, acc10, 0, 0, 0);
        acc11 = __builtin_amdgcn_mfma_f32_16x16x32_bf16(a1, b1f, acc11, 0, 0, 0);
        __syncthreads();
    }
    f32x4 accs[2][2] = { { acc00, acc01 }, { acc10, acc11 } };
#pragma unroll
    for (int mi = 0; mi < 2; ++mi) {
        int co0 = mtile + wm + mi * 16 + (lane >> 4) * 4;
#pragma unroll
        for (int ni = 0; ni < 2; ++ni) {
            int nn = wn + ni * 16 + lr;
            f32x4 v = accs[mi][ni];
            float* dst = &outacc[(long)nn * 1024 + co0];
            atomicAdd(dst + 0, v.x);
            atomicAdd(dst + 1, v.y);
            atomicAdd(dst + 2, v.z);
            atomicAdd(dst + 3, v.w);
        }
    }
}

// ---------------- fc2 split-K: B = relu(fc1acc + fc1_b) staged from f32 -----
__global__ __launch_bounds__(256) void fc2_splitk(
    const __bf16* __restrict__ A, const float* __restrict__ Bacc,
    const float* __restrict__ bb, float* __restrict__ outacc)
{
    __shared__ __attribute__((aligned(16))) __bf16 As[64][40];
    __shared__ __attribute__((aligned(16))) __bf16 Bs[64][40];
    const int tid = threadIdx.x;
    const int mtile = blockIdx.y * 64;
    const int kbase = blockIdx.x * 256;
    const int lane = tid & 63, w = tid >> 6;
    const int wm = (w >> 1) * 32, wn = (w & 1) * 32;
    const int lr = lane & 15, lk = (lane >> 4) * 8;
    const int srow = tid >> 2, soff = (tid & 3) * 8;

    f32x4 acc00 = {}, acc01 = {}, acc10 = {}, acc11 = {};
    for (int k0 = 0; k0 < 256; k0 += 32) {
        int k = kbase + k0 + soff;
        *(bf16x8*)&As[srow][soff] = *(const bf16x8*)&A[(long)(mtile + srow) * 1024 + k];
        f32x4 lo = *(const f32x4*)&Bacc[(long)srow * 1024 + k];
        f32x4 hi = *(const f32x4*)&Bacc[(long)srow * 1024 + k + 4];
        f32x4 blo = *(const f32x4*)&bb[k];
        f32x4 bhi = *(const f32x4*)&bb[k + 4];
        bf16x8 bvv;
        bvv[0] = (__bf16)fmaxf(lo.x + blo.x, 0.f);
        bvv[1] = (__bf16)fmaxf(lo.y + blo.y, 0.f);
        bvv[2] = (__bf16)fmaxf(lo.z + blo.z, 0.f);
        bvv[3] = (__bf16)fmaxf(lo.w + blo.w, 0.f);
        bvv[4] = (__bf16)fmaxf(hi.x + bhi.x, 0.f);
        bvv[5] = (__bf16)fmaxf(hi.y + bhi.y, 0.f);
        bvv[6] = (__bf16)fmaxf(hi.z + bhi.z, 0.f);
        bvv[7] = (__bf16)fmaxf(hi.w + bhi.w, 0.f);
        *(bf16x8*)&Bs[srow][soff] = bvv;
        __syncthreads();
        bf16x8 a0 = *(const bf16x8*)&As[wm + lr][lk];
        bf16x8 a1 = *(const bf16x8*)&As[wm + 16 + lr][lk];
        bf16x8 b0f = *(const bf16x8*)&Bs[wn + lr][lk];
        bf16x8 b1f = *(const bf16x8*)&Bs[wn + 16 + lr][lk];
        acc00 = __builtin_amdgcn_mfma_f32_16x16x32_bf16(a0, b0f, acc00, 0, 0, 0);
        acc01 = __builtin_amdgcn_mfma_f32_16x16x32_bf16(a0, b1f, acc01, 0, 0, 0);
        acc10 = __builtin_amdgcn_mfma_f32_16x16x32_bf16(a1, b0f, acc10, 0, 0, 0);
        acc11 = __builtin_amdgcn_mfma_f32_16x16x32_bf16(a1, b1f, acc11, 0, 0, 0);
        __syncthreads();
    }
    f32x4 accs[2][2] = { { acc00, acc01 }, { acc10, acc11 } };
#pragma unroll
    for (int mi = 0; mi < 2; ++mi) {
        int co0 = mtile + wm + mi * 16 + (lane >> 4) * 4;
#pragma unroll
        for (int ni = 0; ni < 2; ++ni) {
            int nn = wn + ni * 16 + lr;
            f32x4 v = accs[mi][ni];
            float* dst = &outacc[(long)nn * 256 + co0];
            atomicAdd(dst + 0, v.x);
            atomicAdd(dst + 1, v.y);
            atomicAdd(dst + 2, v.z);
            atomicAdd(dst + 3, v.w);
        }
    }
}

// ---------------- GroupNorm(32, cpg=4) NHWC f32 -> bf16 NHWC + relu ---------
__global__ void gn_nhwc(const float* __restrict__ in, const float* __restrict__ s,
                        const float* __restrict__ bi, __bf16* __restrict__ out,
                        int C, int HW)
{
    int b = blockIdx.x >> 5, g = blockIdx.x & 31;
    int tid = threadIdx.x, nt = blockDim.x;
    const float* p = in + (long)b * HW * C + g * 4;
    float sum = 0.f, sq = 0.f;
    for (int i = tid; i < HW; i += nt) {
        f32x4 v = *(const f32x4*)&p[(long)i * C];
        sum += v.x + v.y + v.z + v.w;
        sq  += v.x * v.x + v.y * v.y + v.z * v.z + v.w * v.w;
    }
    __shared__ float rs[256], rq[256];
    rs[tid] = sum; rq[tid] = sq; __syncthreads();
    for (int off = nt >> 1; off > 0; off >>= 1) {
        if (tid < off) { rs[tid] += rs[tid + off]; rq[tid] += rq[tid + off]; }
        __syncthreads();
    }
    int len = HW * 4;
    float mean = rs[0] / len;
    float var  = rq[0] / len - mean * mean;
    float rstd = rsqrtf(fmaxf(var, 0.f) + 1e-5f);
    f32x4 s4 = *(const f32x4*)&s[g * 4];
    f32x4 b4 = *(const f32x4*)&bi[g * 4];
    __bf16* q = out + (long)b * HW * C + g * 4;
    for (int i = tid; i < HW; i += nt) {
        f32x4 v = *(const f32x4*)&p[(long)i * C];
        f32x4 r;
        r.x = fmaxf((v.x - mean) * rstd * s4.x + b4.x, 0.f);
        r.y = fmaxf((v.y - mean) * rstd * s4.y + b4.y, 0.f);
        r.z = fmaxf((v.z - mean) * rstd * s4.z + b4.z, 0.f);
        r.w = fmaxf((v.w - mean) * rstd * s4.w + b4.w, 0.f);
        bf16x4 o4 = { (__bf16)r.x, (__bf16)r.y, (__bf16)r.z, (__bf16)r.w };
        *(bf16x4*)&q[(long)i * C] = o4;
    }
}

// ---------------- heads: wave-per-output, shuffle reduce ---------------------
__global__ __launch_bounds__(576) void head_kern(
    const float* __restrict__ x, const float* __restrict__ fb,
    const float* __restrict__ rw, const float* __restrict__ rb,
    const float* __restrict__ tw, const float* __restrict__ tb,
    const int* __restrict__ obj, float* __restrict__ out)
{
    int b = blockIdx.x;
    int k = threadIdx.x >> 6;        // 0..8
    int lane = threadIdx.x & 63;
    int j = obj[0] - 1;
    const float* xr = x + (long)b * 256;
    const float* wr;
    float bias0;
    if (k < 6) { wr = rw + (long)(j * 6 + k) * 256; bias0 = rb[j * 6 + k]; }
    else       { wr = tw + (long)(j * 3 + (k - 6)) * 256; bias0 = tb[j * 3 + (k - 6)]; }
    float acc = 0.f;
#pragma unroll
    for (int p = 0; p < 4; ++p) {
        int i = lane + p * 64;
        float xv = fmaxf(xr[i] + fb[i], 0.f);
        acc = fmaf(xv, wr[i], acc);
    }
#pragma unroll
    for (int off = 32; off > 0; off >>= 1) acc += __shfl_down(acc, off);
    if (lane == 0) {
        float r = acc + bias0;
        if (k < 6) out[b * 6 + k] = r;
        else       out[384 + b * 3 + (k - 6)] = r;
    }
}

extern "C" void kernel_launch(void* const* d_in, const int* in_sizes, int n_in,
                              void* d_out, int out_size, void* d_ws, size_t ws_size,
                              hipStream_t stream)
{
    const float* hidden = (const float*)d_in[0];
    const float* dflow  = (const float*)d_in[1];
    const float* mask   = (const float*)d_in[2];
    const float* geo    = (const float*)d_in[3];
    const int*   obj    = (const int*)d_in[4];
    const float* g1_w = (const float*)d_in[5],  *g1_b = (const float*)d_in[6];
    const float* g2_w = (const float*)d_in[7],  *g2_b = (const float*)d_in[8];
    const float* d1_w = (const float*)d_in[9],  *d1_b = (const float*)d_in[10];
    const float* d2_w = (const float*)d_in[11], *d2_b = (const float*)d_in[12];
    const float* m1_w = (const float*)d_in[13], *m1_b = (const float*)d_in[14];
    const float* m2_w = (const float*)d_in[15], *m2_b = (const float*)d_in[16];
    const float* c1_w = (const float*)d_in[17], *c1_b = (const float*)d_in[18];
    const float* gn1_s = (const float*)d_in[19], *gn1_bb = (const float*)d_in[20];
    const float* c2_w = (const float*)d_in[21], *c2_b = (const float*)d_in[22];
    const float* gn2_s = (const float*)d_in[23], *gn2_bb = (const float*)d_in[24];
    const float* c3_w = (const float*)d_in[25], *c3_b = (const float*)d_in[26];
    const float* gn3_s = (const float*)d_in[27], *gn3_bb = (const float*)d_in[28];
    const float* fc1_w = (const float*)d_in[29], *fc1_b = (const float*)d_in[30];
    const float* fc2_w = (const float*)d_in[31], *fc2_b = (const float*)d_in[32];
    const float* rot_w = (const float*)d_in[33], *rot_b = (const float*)d_in[34];
    const float* tr_w  = (const float*)d_in[35], *tr_b  = (const float*)d_in[36];

    char* ws = (char*)d_ws;
    __bf16* enc = (__bf16*)ws;                  // NHWC [64,32,32,288] = 37,748,736 B
    char* W = ws + 37748736;
    __bf16* wg1  = (__bf16*)(W + 0);            // [128][96]    24,576
    __bf16* wd1  = (__bf16*)(W + 24576);        // [128][128]   32,768 (mode 3)
    __bf16* wm1  = (__bf16*)(W + 57344);        // [64][128]    16,384
    __bf16* wg2  = (__bf16*)(W + 73728);        // [64][1152]  147,456
    __bf16* wd2  = (__bf16*)(W + 221184);       // [64][1152]  147,456
    __bf16* wm2  = (__bf16*)(W + 368640);       // [64][576]    73,728
    __bf16* wc1  = (__bf16*)(W + 442368);       // [128][2624] 671,744
    __bf16* wc2  = (__bf16*)(W + 1114112);      // [128][1152] 294,912
    __bf16* wc3  = (__bf16*)(W + 1409024);      // [128][1152] 294,912
    __bf16* wfc1 = (__bf16*)(W + 1703936);      // [1024][2048] 4,194,304
    __bf16* wfc2 = (__bf16*)(W + 5898240);      // [256][1024]  524,288
    // transients
    __bf16* geo_p    = (__bf16*)(ws + 44179456);   // [64,64,64,8]    4,194,304
    __bf16* dflow_pp = (__bf16*)(ws + 48373760);   // [64,40,40,2]      409,600
    __bf16* mask_p   = (__bf16*)(ws + 48783360);   // [64,32,32,8]    1,048,576
    __bf16* g1out    = (__bf16*)(ws + 49831936);   // [64,64,64,128] 67,108,864
    __bf16* d1out    = (__bf16*)(ws + 116940800);  // [64,32,32,128] 16,777,216
    __bf16* m1out    = (__bf16*)(ws + 133718016);  // [64,32,32,64]   8,388,608
    float*  c1raw    = (float*)(ws + 142106624);   // [64,16,16,128]  8,388,608
    __bf16* x1       = (__bf16*)(ws + 150495232);  //                 4,194,304
    __bf16* x2       = (__bf16*)(ws + 156786688);  // [64,8,8,128]    1,048,576
    __bf16* x3       = (__bf16*)(ws + 158359552);  // [64][2048]        262,144
    float*  fc1acc   = (float*)(ws + 158621696);   // [64][1024] f32    262,144
    float*  fc2acc   = (float*)(ws + 158883840);   // [64][256]  f32     65,536
    __bf16* zpad     = (__bf16*)(ws + 158949376);  // 4,096 B zero page (prep)

    // ---- PackArgs for prep (only sections 0..2 used: g1, d1, m1) ----
    PackArgs pa;
    {
        const float* srcs[11] = { g1_w, d1_w, m1_w, g2_w, d2_w, m2_w, c1_w, c2_w, c3_w, fc1_w, fc2_w };
        __bf16* dsts[11] = { wg1, wd1, wm1, wg2, wd2, wm2, wc1, wc2, wc3, wfc1, wfc2 };
        int Co[11]  = { 128, 128, 64, 64, 64, 32, 128, 128, 128, 1024, 256 };
        int Ci[11]  = { 8, 2, 1, 128, 128, 64, 288, 128, 128, 0, 0 };
        int KH[11]  = { 9, 49, 9, 9, 9, 9, 9, 9, 9, 0, 0 };
        int KWn[11] = { 3, 7, 3, 3, 3, 3, 3, 3, 3, 0, 0 };
        int Cp[11]  = { 8, 8, 8, 128, 128, 64, 288, 128, 128, 0, 0 };
        int Kp[11]  = { 96, 128, 128, 1152, 1152, 576, 2624, 1152, 1152, 2048, 1024 };
        int Mp[11]  = { 128, 128, 64, 64, 64, 64, 128, 128, 128, 1024, 256 };
        int Md[11]  = { 0, 3, 0, 0, 0, 0, 0, 0, 0, 1, 2 };
        int c = 0; pa.cum[0] = 0;
        for (int i = 0; i < 11; ++i) {
            pa.src[i] = srcs[i]; pa.dst[i] = dsts[i];
            pa.Cout[i] = Co[i]; pa.Cin[i] = Ci[i]; pa.KHW[i] = KH[i]; pa.KW[i] = KWn[i];
            pa.Cinpad[i] = Cp[i]; pa.Kpad[i] = Kp[i]; pa.mode[i] = Md[i];
            c += Mp[i] * Kp[i]; pa.cum[i + 1] = c;
        }
        // cum[3] == 36,864 == PACK_B*256
    }
    // ---- BulkPack for branch1 tail (sections 3..10) ----
    BulkPack bp;
    {
        const float* s[8] = { g2_w, d2_w, m2_w, c1_w, c2_w, c3_w, fc1_w, fc2_w };
        __bf16* d[8] = { wg2, wd2, wm2, wc1, wc2, wc3, wfc1, wfc2 };
        for (int i = 0; i < 8; ++i) { bp.s[i] = s[i]; bp.d[i] = d[i]; }
    }

    // ---- prep: b1 weight packs + vectorized pads + fc-acc/zpad zero ----
    {
        int total_blocks = PACK_B + GEOV_B + DF_B + MASKV_B + ZERO_B;  // 2,305
        prep_kern<<<dim3(total_blocks), 256, 0, stream>>>(pa, geo, geo_p, dflow, dflow_pp,
                                                          mask, mask_p, fc1acc, fc2acc);
    }

    // ConvGeom: CinTot,Hin,Win,log2HWout,log2Wout,stride,pad,Kpad,KHW,Cout,CTOT,C0,b0i,b0o
    // ---- branch stage 1: g1 + d1 + m1 + specialized bulk pack (512 thr) ----
    {
        ConvGeom gg1 = { 8, 64, 64, 12, 6, 1, 1, 96, 9, 128, 128, 0, 0, 0 };
        ConvGeom gd1 = { 2, 40, 40, 10, 5, 1, 0, 128, 49, 128, 128, 0, 0, 0 };
        ConvGeom gm1 = { 8, 32, 32, 10, 5, 1, 1, 128, 9, 64, 64, 0, 0, 0 };
        branch1_kern<<<dim3(B1_CONV + B1_PACK), 512, 0, stream>>>(geo_p, wg1, g1_b, g1out,
                                                                  dflow_pp, wd1, d1_b, d1out,
                                                                  mask_p, wm1, m1_b, m1out,
                                                                  bp, gg1, gd1, gm1);
    }
    // ---- branch stage 2: g2 + d2 + m2 (global_load_lds) + hid -> enc ----
    {
        ConvGeom gg2 = { 128, 64, 64, 10, 5, 2, 1, 1152, 9, 64, 288, 224, 0, 0 };
        ConvGeom gd2 = { 128, 32, 32, 10, 5, 1, 1, 1152, 9, 64, 288, 128, 0, 0 };
        ConvGeom gm2 = { 64, 32, 32, 10, 5, 1, 1, 576, 9, 32, 288, 192, 0, 0 };
        branch2_kern<<<dim3(B2_CONV + B2_HID), 256, 0, stream>>>(g1out, wg2, g2_b,
                                                                 d1out, wd2, d2_b,
                                                                 m1out, wm2, m2_b,
                                                                 hidden, enc, zpad,
                                                                 gg2, gd2, gm2);
    }

    // ---- c1 + GN1 (BM=64 BN=128 wave 64x32, grid (128,2)) ----
    {
        ConvGeom gc1 = { 288, 32, 32, 8, 4, 2, 1, 2624, 9, 128, 128, 0, 0, 0 };
        conv_gemm2<64, 128, 64, 256, 1, 4, 288, 3, 0, false, false><<<dim3(128, 2), 256, 0, stream>>>(enc, wc1, c1_b, c1raw, gc1);
    }
    gn_nhwc<<<dim3(2048), 256, 0, stream>>>(c1raw, gn1_s, gn1_bb, x1, 128, 256);

    // ---- c2 fused GN2 (BN=64 = 1 batch x 64 px) ----
    {
        ConvGeom gc2 = { 128, 16, 16, 6, 3, 2, 1, 1152, 9, 128, 128, 0, 0, 0 };
        conv_gn_kern<64, 64, 64, 256, 2, 2, 128, 3, 64><<<dim3(64, 2), 256, 0, stream>>>(
            x1, wc2, c2_b, gn2_s, gn2_bb, x2, gc2);
    }
    // ---- c3 fused GN3 (BN=64 = 4 batches x 16 px) ----
    {
        ConvGeom gc3 = { 128, 8, 8, 4, 2, 2, 1, 1152, 9, 128, 128, 0, 0, 0 };
        conv_gn_kern<64, 64, 64, 256, 2, 2, 128, 3, 16><<<dim3(16, 2), 256, 0, stream>>>(
            x2, wc3, c3_b, gn3_s, gn3_bb, x3, gc3);
    }

    // ---- fc1 (split-K atomic), fc2 (split-K, B = relu(fc1acc+b)) ----
    fc1_splitk<<<dim3(4, 16), 256, 0, stream>>>(wfc1, x3, fc1acc);
    fc2_splitk<<<dim3(4, 4), 256, 0, stream>>>(wfc2, fc1acc, fc1_b, fc2acc);

    // ---- heads (applies fc2 bias + relu; 64 blocks x 9 waves) ----
    head_kern<<<dim3(64), 576, 0, stream>>>(fc2acc, fc2_b, rot_w, rot_b, tr_w, tr_b, obj, (float*)d_out);
}

// Round 14
// 199.682 us; speedup vs baseline: 1.0459x; 1.0459x over previous
//
#include <hip/hip_runtime.h>
#include <hip/hip_bf16.h>

typedef __bf16 bf16x8 __attribute__((ext_vector_type(8)));
typedef __bf16 bf16x4 __attribute__((ext_vector_type(4)));
typedef float  f32x4  __attribute__((ext_vector_type(4)));

__device__ __forceinline__ void gload16(const void* g, void* l)
{
    __builtin_amdgcn_global_load_lds((const __attribute__((address_space(1))) void*)g,
                                     (__attribute__((address_space(3))) void*)l, 16, 0, 0);
}

// ---------------- weight pack (generic, prep-only: g1/d1/m1 sections) -------
struct PackArgs {
    const float* src[11];
    __bf16* dst[11];
    int Cout[11], Cin[11], KHW[11], KW[11], Cinpad[11], Kpad[11], mode[11];
    int cum[12];
};

__device__ void pack_dev(const PackArgs& pa, int gidx)
{
    if (gidx >= pa.cum[11]) return;
    int s = 0;
    for (int i = 1; i <= 10; ++i) s += (gidx >= pa.cum[i]) ? 1 : 0;
    int l = gidx - pa.cum[s];
    int Kp = pa.Kpad[s];
    int co = l / Kp, k = l - co * Kp;
    float v = 0.f;
    if (co < pa.Cout[s]) {
        if (pa.mode[s] == 0) {
            int cip = pa.Cinpad[s];
            int tap = k / cip, ci = k - tap * cip;
            if (tap < pa.KHW[s] && ci < pa.Cin[s])
                v = pa.src[s][((long)co * pa.Cin[s] + ci) * pa.KHW[s] + tap];
        } else if (pa.mode[s] == 1) {
            int pix = k >> 7, c = k & 127;
            v = pa.src[s][(long)co * 2048 + c * 16 + pix];
        } else if (pa.mode[s] == 2) {
            v = pa.src[s][(long)co * Kp + k];
        } else {  // mode 3: d1
            int kh = k >> 4, r = k & 15, kw = r >> 1, ci = r & 1;
            if (kh < 7 && kw < 7)
                v = pa.src[s][((long)(co * 2 + ci) * 7 + kh) * 7 + kw];
        }
    }
    pa.dst[s][l] = (__bf16)v;
}

// ---------------- specialized bulk packers (branch1 tail, 8 elems/thread) ---
struct BulkPack { const float* s[8]; __bf16* d[8]; };

template<int CO, int CIN, int KP>
__device__ __forceinline__ void pack_conv8(const float* __restrict__ src,
                                           __bf16* __restrict__ dst, int eb)
{
    int e = eb * 8;
    int co = e / KP;
    int k  = e - co * KP;
    int tap = k / CIN;
    int ci  = k - tap * CIN;
    bf16x8 o = {};
    if (co < CO && tap < 9) {
        const float* s = src + ((long)co * CIN + ci) * 9 + tap;
#pragma unroll
        for (int j = 0; j < 8; ++j) o[j] = (__bf16)s[j * 9];
    }
    *(bf16x8*)&dst[e] = o;
}

__device__ __forceinline__ void pack_fc1_8(const float* __restrict__ src,
                                           __bf16* __restrict__ dst, int eb)
{
    int e = eb * 8;
    int co = e >> 11, k = e & 2047;
    int pix = k >> 7, c = k & 127;
    const float* s = src + (long)co * 2048 + c * 16 + pix;
    bf16x8 o;
#pragma unroll
    for (int j = 0; j < 8; ++j) o[j] = (__bf16)s[j * 16];
    *(bf16x8*)&dst[e] = o;
}

__device__ __forceinline__ void pack_fc2_8(const float* __restrict__ src,
                                           __bf16* __restrict__ dst, int eb)
{
    int e = eb * 8;
    f32x4 lo = *(const f32x4*)&src[e];
    f32x4 hi = *(const f32x4*)&src[e + 4];
    bf16x8 o = { (__bf16)lo.x, (__bf16)lo.y, (__bf16)lo.z, (__bf16)lo.w,
                 (__bf16)hi.x, (__bf16)hi.y, (__bf16)hi.z, (__bf16)hi.w };
    *(bf16x8*)&dst[e] = o;
}

// ---------------- NCHW f32 (C<=8) -> NHWC8 bf16, vectorized (pixel/thread) --
__device__ void pad_nhwc8v_dev(const float* __restrict__ in, __bf16* __restrict__ out,
                               int C, int log2HW, int pidx)
{
    int b = pidx >> log2HW;
    int pix = pidx & ((1 << log2HW) - 1);
    const float* s = in + (((long)b * C) << log2HW) + pix;
    bf16x8 o = {};
    for (int c = 0; c < C; ++c) o[c] = (__bf16)s[(long)c << log2HW];
    *(bf16x8*)&out[(long)pidx * 8] = o;
}

// ---------------- dflow NCHW [64,2,32,32] -> padded NHWC [64,40,40,2] -------
__device__ void pad_dflow_dev(const float* __restrict__ in, __bf16* __restrict__ out, int idx)
{
    if (idx >= 64 * 40 * 40 * 2) return;
    int c = idx & 1;
    int t = idx >> 1;
    int x = t % 40;
    int t2 = t / 40;
    int y = t2 % 40;
    int b = t2 / 40;
    int hi = y - 3, wi = x - 3;
    float v = 0.f;
    if ((unsigned)hi < 32u && (unsigned)wi < 32u)
        v = in[((long)(b * 2 + c) * 32 + hi) * 32 + wi];
    out[idx] = (__bf16)v;
}

// ---------------- hidden NCHW f32 -> enc NHWC bf16 channels 0..127 ----------
__device__ void hid_dev(char* smem, const float* __restrict__ h,
                        __bf16* __restrict__ enc, int blk, int tid)
{
    auto t = reinterpret_cast<float (*)[65]>(smem);
    int b = blk >> 6;
    int inner = blk & 63;
    int ct = inner & 3, pt = inner >> 2;
    int c0 = ct * 32, p0 = pt * 64;
    int cl = tid >> 6, pl = tid & 63;
#pragma unroll
    for (int i = 0; i < 8; ++i)
        t[cl + i * 4][pl] = h[((long)(b * 128 + c0 + cl + i * 4)) * 1024 + p0 + pl];
    __syncthreads();
    int cc = tid & 31, p2 = tid >> 5;
#pragma unroll
    for (int i = 0; i < 8; ++i)
        enc[((long)b * 1024 + p0 + p2 + i * 8) * 288 + c0 + cc] = (__bf16)t[cc][p2 + i * 8];
}

// ---------------- prep: b1 weight packs + vectorized pads + zeroing ---------
#define PACK_B 144
#define GEOV_B 1024
#define DF_B 800
#define MASKV_B 256
#define ZERO_B 81
// total 2,305
__global__ __launch_bounds__(256) void prep_kern(PackArgs pa,
    const float* __restrict__ geo, __bf16* __restrict__ geo_p,
    const float* __restrict__ dflow, __bf16* __restrict__ dflow_pp,
    const float* __restrict__ mask, __bf16* __restrict__ mask_p,
    float* __restrict__ fc1acc, float* __restrict__ fc2acc)
{
    int blk = blockIdx.x, tid = threadIdx.x;
    if (blk < PACK_B) { pack_dev(pa, blk * 256 + tid); return; }
    blk -= PACK_B;
    if (blk < GEOV_B) { pad_nhwc8v_dev(geo, geo_p, 8, 12, blk * 256 + tid); return; }
    blk -= GEOV_B;
    if (blk < DF_B) { pad_dflow_dev(dflow, dflow_pp, blk * 256 + tid); return; }
    blk -= DF_B;
    if (blk < MASKV_B) { pad_nhwc8v_dev(mask, mask_p, 1, 10, blk * 256 + tid); return; }
    blk -= MASKV_B;
    long zi = (long)blk * 256 + tid;
    f32x4 z = {};
    if (zi < 16384) *(f32x4*)&fc1acc[zi * 4] = z;            // 64x1024 f32
    else { zi -= 16384; *(f32x4*)&fc2acc[zi * 4] = z; }      // 64x256 f32 + 4KB zpad
}

// ---------------- implicit-GEMM conv, NHWC, reg-prefetch --------------------
struct ConvGeom {
    int CinTot;
    int Hin, Win;
    int log2HWout, log2Wout;
    int stride, pad;
    int Kpad;                   // multiple of BK
    int KHW;
    int Cout, CTOT, C0;
    int b0i, b0o;
};

// ======== conv_dev3: branch2-specialized (BM=64, BN=128, BK=64, 256 thr) ====
// Double-buffered global_load_lds staging (2 x 24KB LDS): DMA for K-step k+1
// issued BEFORE compute on k, single barrier per step (loads fly under MFMA).
// Linear LDS dest + source-pre-swizzled XOR; swizzled ds_read (0 conflicts,
// verified R13). Boundary lanes read a zero page.
template<int CINPAD>
__device__ __forceinline__ void conv_dev3(char* __restrict__ smem_, int bx,
    const __bf16* __restrict__ in_, const __bf16* __restrict__ A,
    const float* __restrict__ bias, __bf16* __restrict__ out_,
    const ConvGeom& g, const __bf16* __restrict__ zpad)
{
    constexpr int BM = 64, BN = 128, BK = 64;
    constexpr int ABYTES = BM * BK * 2;   // 8192
    constexpr int BUF = 24576;
    const int tid = threadIdx.x;
    const int w4 = tid >> 6, l = tid & 63;
    const int lane = l;
    const int wn = w4 * 32;               // WMW=1 (wm=0), WNW=4
    const int lr = lane & 15, lk = (lane >> 4) * 8;
    const int ntile = bx * BN;

    // A staging lane constants: LDS byte X -> (row, data col) with XOR swizzle
    int rowA[2], colA[2];
#pragma unroll
    for (int j = 0; j < 2; ++j) {
        int X = ((w4 * 2 + j) << 10) + l * 16;
        rowA[j] = X >> 7;
        int cb = (X & 127) ^ ((rowA[j] & 7) << 4);
        colA[j] = cb >> 1;
    }
    // B staging lane constants
    int rowB[4], colB[4], hi0a[4], wi0a[4];
    long nbase[4];
#pragma unroll
    for (int j = 0; j < 4; ++j) {
        int X = ((w4 * 4 + j) << 10) + l * 16;
        rowB[j] = X >> 7;
        int cb = (X & 127) ^ ((rowB[j] & 7) << 4);
        colB[j] = cb >> 1;
        int n = ntile + rowB[j];
        int bb = g.b0i + (n >> g.log2HWout);
        int pix = n & ((1 << g.log2HWout) - 1);
        int ho = pix >> g.log2Wout, wo = pix & ((1 << g.log2Wout) - 1);
        hi0a[j] = ho * g.stride - g.pad;
        wi0a[j] = wo * g.stride - g.pad;
        nbase[j] = (((long)bb * g.Hin + hi0a[j]) * g.Win + wi0a[j]) * g.CinTot;
    }

    auto STAGE = [&](int k0, char* base) {
#pragma unroll
        for (int j = 0; j < 2; ++j) {
            const __bf16* ga = A + (long)rowA[j] * g.Kpad + k0 + colA[j];
            gload16(ga, base + ((w4 * 2 + j) << 10));
        }
        int tap = k0 / CINPAD;
        int ci0 = k0 % CINPAD;
        int kh = tap / 3, kw = tap - kh * 3;
        int toff = (kh * g.Win + kw) * g.CinTot + ci0;
#pragma unroll
        for (int j = 0; j < 4; ++j) {
            int hi = hi0a[j] + kh, wi = wi0a[j] + kw;
            bool v = (unsigned)hi < (unsigned)g.Hin && (unsigned)wi < (unsigned)g.Win;
            const __bf16* gb = v ? (in_ + nbase[j] + toff + colB[j]) : (zpad + l * 8);
            gload16(gb, base + ABYTES + ((w4 * 4 + j) << 10));
        }
    };

    f32x4 acc[4][2] = {};
    STAGE(0, smem_);
    __syncthreads();                        // drain DMA for tile 0
    int cur = 0;
    for (int k0 = 0;;) {
        int kn = k0 + BK;
        bool more = kn < g.Kpad;
        if (more) STAGE(kn, smem_ + (cur ^ 1) * BUF);   // next tile flies under MFMA
        char* base = smem_ + cur * BUF;
#pragma unroll
        for (int kk = 0; kk < BK; kk += 32) {
            bf16x8 bfr[2], afr[4];
#pragma unroll
            for (int jn = 0; jn < 2; ++jn) {
                int row = wn + jn * 16 + lr;
                int byte = ABYTES + row * 128 + (((kk + lk) * 2) ^ ((row & 7) << 4));
                bfr[jn] = *(const bf16x8*)(base + byte);
            }
#pragma unroll
            for (int i = 0; i < 4; ++i) {
                int row = i * 16 + lr;
                int byte = row * 128 + (((kk + lk) * 2) ^ ((row & 7) << 4));
                afr[i] = *(const bf16x8*)(base + byte);
            }
#pragma unroll
            for (int i = 0; i < 4; ++i) {
                acc[i][0] = __builtin_amdgcn_mfma_f32_16x16x32_bf16(afr[i], bfr[0], acc[i][0], 0, 0, 0);
                acc[i][1] = __builtin_amdgcn_mfma_f32_16x16x32_bf16(afr[i], bfr[1], acc[i][1], 0, 0, 0);
            }
        }
        if (!more) break;
        __syncthreads();                    // next-tile DMA done + reads of cur done
        cur ^= 1;
        k0 = kn;
    }

    const int HWm1 = (1 << g.log2HWout) - 1;
#pragma unroll
    for (int i = 0; i < 4; ++i) {
        int co = i * 16 + (lane >> 4) * 4;
        if (co >= g.Cout) continue;
        f32x4 bv4 = *(const f32x4*)&bias[co];
#pragma unroll
        for (int jn = 0; jn < 2; ++jn) {
            int nn = ntile + wn + jn * 16 + lr;
            f32x4 v = acc[i][jn] + bv4;
            v.x = fmaxf(v.x, 0.f); v.y = fmaxf(v.y, 0.f);
            v.z = fmaxf(v.z, 0.f); v.w = fmaxf(v.w, 0.f);
            int ob = nn >> g.log2HWout, opix = nn & HWm1;
            long o = (((long)(g.b0o + ob) << g.log2HWout) + opix) * g.CTOT + g.C0 + co;
            bf16x4 o4 = { (__bf16)v.x, (__bf16)v.y, (__bf16)v.z, (__bf16)v.w };
            *(bf16x4*)&out_[o] = o4;
        }
    }
}

// ======== conv_dev2: generalized wave tiling (c1 + c2f/c3f host) ============
template<int BM, int BN, int BK, int THREADS, int WMW, int WNW, int CINPAD, int KW, int MODE, bool OUTBF, bool RELU>
__device__ __forceinline__ void conv_dev2(char* __restrict__ smem_, int bx,
    const __bf16* __restrict__ in_, const __bf16* __restrict__ A,
    const float* __restrict__ bias, void* __restrict__ out_, const ConvGeom& g)
{
    constexpr int MEXT = BM / WMW;
    constexpr int NEXT = BN / WNW;
    constexpr int MFRAG = MEXT / 16;
    constexpr int NFRAG = NEXT / 16;
    constexpr int KROW = BK / 8;
    constexpr int SROWS = THREADS / KROW;
    constexpr int APASS = BM / SROWS;
    constexpr int BPASS = BN / SROWS;
    constexpr int LDK = BK + 8;

    auto As = reinterpret_cast<__bf16 (*)[LDK]>(smem_);
    auto Bs = reinterpret_cast<__bf16 (*)[LDK]>(smem_ + (size_t)BM * LDK * sizeof(__bf16));

    const int tid = threadIdx.x;
    const int ntile = bx * BN;
    const int lane = tid & 63, w = tid >> 6;
    const int wm = (w / WNW) * MEXT, wn = (w % WNW) * NEXT;
    const int lr = lane & 15, lk = (lane >> 4) * 8;
    const int srow = tid / KROW, scol = (tid % KROW) * 8;

    long nbase[BPASS]; int hi0a[BPASS], wi0a[BPASS];
#pragma unroll
    for (int j = 0; j < BPASS; ++j) {
        int n = ntile + j * SROWS + srow;
        int bb = g.b0i + (n >> g.log2HWout);
        int pix = n & ((1 << g.log2HWout) - 1);
        int ho = pix >> g.log2Wout, wo = pix & ((1 << g.log2Wout) - 1);
        hi0a[j] = ho * g.stride - g.pad;
        wi0a[j] = wo * g.stride - g.pad;
        nbase[j] = (((long)bb * g.Hin + hi0a[j]) * g.Win + wi0a[j]) * g.CinTot;
    }

    bf16x8 av[APASS], bv[BPASS];
    auto LOAD = [&](int k0) {
        int k = k0 + scol;
#pragma unroll
        for (int ja = 0; ja < APASS; ++ja)
            av[ja] = *(const bf16x8*)&A[(long)(ja * SROWS + srow) * g.Kpad + k];
        if (MODE == 1) {
            int q = k >> 3;
            int off = (q >> 1) * (g.Win * g.CinTot) + (q & 1) * 8;
#pragma unroll
            for (int j = 0; j < BPASS; ++j)
                bv[j] = *(const bf16x8*)&in_[nbase[j] + off];
        } else {
            int tap = k / CINPAD;
            int ci  = k - tap * CINPAD;
            int kh  = tap / KW;
            int kw  = tap - kh * KW;
            bool tv = tap < g.KHW;
            int off = (kh * g.Win + kw) * g.CinTot + ci;
#pragma unroll
            for (int j = 0; j < BPASS; ++j) {
                bf16x8 z = {};
                int hi = hi0a[j] + kh, wi = wi0a[j] + kw;
                if (tv && (unsigned)hi < (unsigned)g.Hin && (unsigned)wi < (unsigned)g.Win)
                    z = *(const bf16x8*)&in_[nbase[j] + off];
                bv[j] = z;
            }
        }
    };

    f32x4 acc[MFRAG][NFRAG] = {};
    LOAD(0);
    for (int k0 = 0;;) {
        if (k0) __syncthreads();
#pragma unroll
        for (int ja = 0; ja < APASS; ++ja)
            *(bf16x8*)&As[ja * SROWS + srow][scol] = av[ja];
#pragma unroll
        for (int j = 0; j < BPASS; ++j)
            *(bf16x8*)&Bs[j * SROWS + srow][scol] = bv[j];
        __syncthreads();
        int kn = k0 + BK;
        bool more = kn < g.Kpad;
        if (more) LOAD(kn);
#pragma unroll
        for (int kk = 0; kk < BK; kk += 32) {
            bf16x8 bfr[NFRAG], afr[MFRAG];
#pragma unroll
            for (int jn = 0; jn < NFRAG; ++jn)
                bfr[jn] = *(const bf16x8*)&Bs[wn + jn * 16 + lr][kk + lk];
#pragma unroll
            for (int i = 0; i < MFRAG; ++i)
                afr[i] = *(const bf16x8*)&As[wm + i * 16 + lr][kk + lk];
#pragma unroll
            for (int i = 0; i < MFRAG; ++i)
#pragma unroll
                for (int jn = 0; jn < NFRAG; ++jn)
                    acc[i][jn] = __builtin_amdgcn_mfma_f32_16x16x32_bf16(afr[i], bfr[jn], acc[i][jn], 0, 0, 0);
        }
        if (!more) break;
        k0 = kn;
    }

    const int HWm1 = (1 << g.log2HWout) - 1;
#pragma unroll
    for (int i = 0; i < MFRAG; ++i) {
        int co = wm + i * 16 + (lane >> 4) * 4;
        if (co >= g.Cout) continue;
        f32x4 bv4 = *(const f32x4*)&bias[co];
#pragma unroll
        for (int jn = 0; jn < NFRAG; ++jn) {
            int nn = ntile + wn + jn * 16 + lr;
            f32x4 v = acc[i][jn] + bv4;
            if (RELU) { v.x = fmaxf(v.x, 0.f); v.y = fmaxf(v.y, 0.f); v.z = fmaxf(v.z, 0.f); v.w = fmaxf(v.w, 0.f); }
            int ob = nn >> g.log2HWout, opix = nn & HWm1;
            long o = (((long)(g.b0o + ob) << g.log2HWout) + opix) * g.CTOT + g.C0 + co;
            if (OUTBF) {
                bf16x4 o4 = { (__bf16)v.x, (__bf16)v.y, (__bf16)v.z, (__bf16)v.w };
                *(bf16x4*)&((__bf16*)out_)[o] = o4;
            } else {
                *(f32x4*)&((float*)out_)[o] = v;
            }
        }
    }
}

// ======== legacy conv_dev (branch1 short-K convs) ===========================
template<int BM, int BN, int BK, int THREADS, int CINPAD, int KW, int MODE, bool OUTBF, bool RELU>
__device__ __forceinline__ void conv_dev(char* __restrict__ smem_, int bx,
    const __bf16* __restrict__ in_, const __bf16* __restrict__ A,
    const float* __restrict__ bias, void* __restrict__ out_, const ConvGeom& g)
{
    constexpr int WAVES = THREADS / 64;
    constexpr int WN = BN / 32;
    constexpr int WM = WAVES / WN;
    constexpr int MEXT = BM / WM;
    constexpr int MFRAG = MEXT / 16;
    constexpr int KROW = BK / 8;
    constexpr int SROWS = THREADS / KROW;
    constexpr int APASS = BM / SROWS;
    constexpr int BPASS = BN / SROWS;

    auto As = reinterpret_cast<__bf16 (*)[BK + 8]>(smem_);
    auto Bs = reinterpret_cast<__bf16 (*)[BK + 8]>(smem_ + (size_t)BM * (BK + 8) * sizeof(__bf16));

    const int tid = threadIdx.x;
    const int ntile = bx * BN;
    const int lane = tid & 63, w = tid >> 6;
    const int wm = (w / WN) * MEXT, wn = (w % WN) * 32;
    const int lr = lane & 15, lk = (lane >> 4) * 8;
    const int srow = tid / KROW, scol = (tid % KROW) * 8;

    long nbase[BPASS]; int hi0a[BPASS], wi0a[BPASS];
#pragma unroll
    for (int j = 0; j < BPASS; ++j) {
        int n = ntile + j * SROWS + srow;
        int bb = g.b0i + (n >> g.log2HWout);
        int pix = n & ((1 << g.log2HWout) - 1);
        int ho = pix >> g.log2Wout, wo = pix & ((1 << g.log2Wout) - 1);
        hi0a[j] = ho * g.stride - g.pad;
        wi0a[j] = wo * g.stride - g.pad;
        nbase[j] = (((long)bb * g.Hin + hi0a[j]) * g.Win + wi0a[j]) * g.CinTot;
    }

    bf16x8 av[APASS], bv[BPASS];
    auto LOAD = [&](int k0) {
        int k = k0 + scol;
#pragma unroll
        for (int ja = 0; ja < APASS; ++ja)
            av[ja] = *(const bf16x8*)&A[(long)(ja * SROWS + srow) * g.Kpad + k];
        if (MODE == 1) {
            int q = k >> 3;
            int off = (q >> 1) * (g.Win * g.CinTot) + (q & 1) * 8;
#pragma unroll
            for (int j = 0; j < BPASS; ++j)
                bv[j] = *(const bf16x8*)&in_[nbase[j] + off];
        } else {
            int tap = k / CINPAD;
            int ci  = k - tap * CINPAD;
            int kh  = tap / KW;
            int kw  = tap - kh * KW;
            bool tv = tap < g.KHW;
            int off = (kh * g.Win + kw) * g.CinTot + ci;
#pragma unroll
            for (int j = 0; j < BPASS; ++j) {
                bf16x8 z = {};
                int hi = hi0a[j] + kh, wi = wi0a[j] + kw;
                if (tv && (unsigned)hi < (unsigned)g.Hin && (unsigned)wi < (unsigned)g.Win)
                    z = *(const bf16x8*)&in_[nbase[j] + off];
                bv[j] = z;
            }
        }
    };

    f32x4 acc[MFRAG][2] = {};
    LOAD(0);
    for (int k0 = 0;;) {
        if (k0) __syncthreads();
#pragma unroll
        for (int ja = 0; ja < APASS; ++ja)
            *(bf16x8*)&As[ja * SROWS + srow][scol] = av[ja];
#pragma unroll
        for (int j = 0; j < BPASS; ++j)
            *(bf16x8*)&Bs[j * SROWS + srow][scol] = bv[j];
        __syncthreads();
        int kn = k0 + BK;
        bool more = kn < g.Kpad;
        if (more) LOAD(kn);
#pragma unroll
        for (int kk = 0; kk < BK; kk += 32) {
            bf16x8 bfr[2];
            bfr[0] = *(const bf16x8*)&Bs[wn + lr][kk + lk];
            bfr[1] = *(const bf16x8*)&Bs[wn + 16 + lr][kk + lk];
#pragma unroll
            for (int i = 0; i < MFRAG; ++i) {
                bf16x8 a = *(const bf16x8*)&As[wm + i * 16 + lr][kk + lk];
                acc[i][0] = __builtin_amdgcn_mfma_f32_16x16x32_bf16(a, bfr[0], acc[i][0], 0, 0, 0);
                acc[i][1] = __builtin_amdgcn_mfma_f32_16x16x32_bf16(a, bfr[1], acc[i][1], 0, 0, 0);
            }
        }
        if (!more) break;
        k0 = kn;
    }

    const int HWm1 = (1 << g.log2HWout) - 1;
#pragma unroll
    for (int i = 0; i < MFRAG; ++i) {
        int co = wm + i * 16 + (lane >> 4) * 4;
        if (co >= g.Cout) continue;
        f32x4 bv4 = *(const f32x4*)&bias[co];
#pragma unroll
        for (int jb = 0; jb < 2; ++jb) {
            int nn = ntile + wn + jb * 16 + lr;
            f32x4 v = acc[i][jb] + bv4;
            if (RELU) { v.x = fmaxf(v.x, 0.f); v.y = fmaxf(v.y, 0.f); v.z = fmaxf(v.z, 0.f); v.w = fmaxf(v.w, 0.f); }
            int ob = nn >> g.log2HWout, opix = nn & HWm1;
            long o = (((long)(g.b0o + ob) << g.log2HWout) + opix) * g.CTOT + g.C0 + co;
            if (OUTBF) {
                bf16x4 o4 = { (__bf16)v.x, (__bf16)v.y, (__bf16)v.z, (__bf16)v.w };
                *(bf16x4*)&((__bf16*)out_)[o] = o4;
            } else {
                *(f32x4*)&((float*)out_)[o] = v;
            }
        }
    }
}

// ---- standalone conv with M-split grid (c1): grid = (ntiles, mtiles) --------
template<int BM, int BN, int BK, int THREADS, int WMW, int WNW, int CINPAD, int KW, int MODE, bool OUTBF, bool RELU>
__global__ __launch_bounds__(THREADS) void conv_gemm2(
    const __bf16* __restrict__ in_, const __bf16* __restrict__ A,
    const float* __restrict__ bias, void* __restrict__ out_, ConvGeom g)
{
    __shared__ __attribute__((aligned(16))) char smem[(BM + BN) * (BK + 8) * 2];
    int mt = blockIdx.y * BM;
    ConvGeom gg = g;
    gg.C0 += mt;
    gg.Cout -= mt;
    conv_dev2<BM, BN, BK, THREADS, WMW, WNW, CINPAD, KW, MODE, OUTBF, RELU>(
        smem, blockIdx.x, in_, A + (long)mt * g.Kpad, bias + mt, out_, gg);
}

// ======== conv + fused GroupNorm(cpg=4) + relu (c2/c3) ======================
template<int BM, int BN, int BK, int THREADS, int WMW, int WNW, int CINPAD, int KW, int PPB>
__global__ __launch_bounds__(THREADS) void conv_gn_kern(
    const __bf16* __restrict__ in_, const __bf16* __restrict__ A,
    const float* __restrict__ bias, const float* __restrict__ gns,
    const float* __restrict__ gnb, __bf16* __restrict__ out_, ConvGeom g)
{
    constexpr int MEXT = BM / WMW;
    constexpr int NEXT = BN / WNW;
    constexpr int MFRAG = MEXT / 16;
    constexpr int NFRAG = NEXT / 16;
    constexpr int KROW = BK / 8;
    constexpr int SROWS = THREADS / KROW;
    constexpr int APASS = BM / SROWS;
    constexpr int BPASS = BN / SROWS;
    constexpr int LDK = BK + 8;

    __shared__ __attribute__((aligned(16))) char smem_[(BM + BN) * (BK + 8) * 2];
    auto As = reinterpret_cast<__bf16 (*)[LDK]>(smem_);
    auto Bs = reinterpret_cast<__bf16 (*)[LDK]>(smem_ + (size_t)BM * LDK * sizeof(__bf16));
    static_assert((size_t)BN * (BM + 4) * 4 <= (size_t)(BM + BN) * (BK + 8) * 2, "smf fits");

    const int tid = threadIdx.x;
    const int mt = blockIdx.y * BM;
    const __bf16* Ap = A + (long)mt * g.Kpad;
    const int C0 = g.C0 + mt;
    const int ntile = blockIdx.x * BN;
    const int lane = tid & 63, w = tid >> 6;
    const int wm = (w / WNW) * MEXT, wn = (w % WNW) * NEXT;
    const int lr = lane & 15, lk = (lane >> 4) * 8;
    const int srow = tid / KROW, scol = (tid % KROW) * 8;

    long nbase[BPASS]; int hi0a[BPASS], wi0a[BPASS];
#pragma unroll
    for (int j = 0; j < BPASS; ++j) {
        int n = ntile + j * SROWS + srow;
        int bb = g.b0i + (n >> g.log2HWout);
        int pix = n & ((1 << g.log2HWout) - 1);
        int ho = pix >> g.log2Wout, wo = pix & ((1 << g.log2Wout) - 1);
        hi0a[j] = ho * g.stride - g.pad;
        wi0a[j] = wo * g.stride - g.pad;
        nbase[j] = (((long)bb * g.Hin + hi0a[j]) * g.Win + wi0a[j]) * g.CinTot;
    }

    bf16x8 av[APASS], bv[BPASS];
    auto LOAD = [&](int k0) {
        int k = k0 + scol;
#pragma unroll
        for (int ja = 0; ja < APASS; ++ja)
            av[ja] = *(const bf16x8*)&Ap[(long)(ja * SROWS + srow) * g.Kpad + k];
        int tap = k / CINPAD;
        int ci  = k - tap * CINPAD;
        int kh  = tap / KW;
        int kw  = tap - kh * KW;
        bool tv = tap < g.KHW;
        int off = (kh * g.Win + kw) * g.CinTot + ci;
#pragma unroll
        for (int j = 0; j < BPASS; ++j) {
            bf16x8 z = {};
            int hi = hi0a[j] + kh, wi = wi0a[j] + kw;
            if (tv && (unsigned)hi < (unsigned)g.Hin && (unsigned)wi < (unsigned)g.Win)
                z = *(const bf16x8*)&in_[nbase[j] + off];
            bv[j] = z;
        }
    };

    f32x4 acc[MFRAG][NFRAG] = {};
    LOAD(0);
    for (int k0 = 0;;) {
        if (k0) __syncthreads();
#pragma unroll
        for (int ja = 0; ja < APASS; ++ja)
            *(bf16x8*)&As[ja * SROWS + srow][scol] = av[ja];
#pragma unroll
        for (int j = 0; j < BPASS; ++j)
            *(bf16x8*)&Bs[j * SROWS + srow][scol] = bv[j];
        __syncthreads();
        int kn = k0 + BK;
        bool more = kn < g.Kpad;
        if (more) LOAD(kn);
#pragma unroll
        for (int kk = 0; kk < BK; kk += 32) {
            bf16x8 bfr[NFRAG], afr[MFRAG];
#pragma unroll
            for (int jn = 0; jn < NFRAG; ++jn)
                bfr[jn] = *(const bf16x8*)&Bs[wn + jn * 16 + lr][kk + lk];
#pragma unroll
            for (int i = 0; i < MFRAG; ++i)
                afr[i] = *(const bf16x8*)&As[wm + i * 16 + lr][kk + lk];
#pragma unroll
            for (int i = 0; i < MFRAG; ++i)
#pragma unroll
                for (int jn = 0; jn < NFRAG; ++jn)
                    acc[i][jn] = __builtin_amdgcn_mfma_f32_16x16x32_bf16(afr[i], bfr[jn], acc[i][jn], 0, 0, 0);
        }
        if (!more) break;
        k0 = kn;
    }

    // ---- fused GN epilogue ----
    __syncthreads();
    auto smf = reinterpret_cast<float (*)[BM + 4]>(smem_);
#pragma unroll
    for (int i = 0; i < MFRAG; ++i) {
        int m = wm + i * 16 + (lane >> 4) * 4;
        f32x4 bv4 = *(const f32x4*)&bias[C0 + m];
#pragma unroll
        for (int jn = 0; jn < NFRAG; ++jn) {
            int n = wn + jn * 16 + lr;
            *(f32x4*)&smf[n][m] = acc[i][jn] + bv4;
        }
    }
    __syncthreads();

    constexpr int NSETS = (BN / PPB) * (BM / 4);
    constexpr int TPS = THREADS / NSETS;
    constexpr int PPT = PPB / TPS;
    const int set = tid / TPS, part = tid % TPS;
    const int bit = set / (BM / 4);
    const int grp = set % (BM / 4);
    const int m0 = grp * 4;
    float sum = 0.f, sq = 0.f;
#pragma unroll
    for (int p = 0; p < PPT; ++p) {
        int nl = bit * PPB + part + p * TPS;
        f32x4 v = *(const f32x4*)&smf[nl][m0];
        sum += v.x + v.y + v.z + v.w;
        sq  += v.x * v.x + v.y * v.y + v.z * v.z + v.w * v.w;
    }
#pragma unroll
    for (int off = TPS >> 1; off > 0; off >>= 1) {
        sum += __shfl_xor(sum, off);
        sq  += __shfl_xor(sq, off);
    }
    const float len = (float)(PPB * 4);
    float mean = sum / len;
    float var  = sq / len - mean * mean;
    float rstd = rsqrtf(fmaxf(var, 0.f) + 1e-5f);
    f32x4 s4 = *(const f32x4*)&gns[C0 + m0];
    f32x4 b4 = *(const f32x4*)&gnb[C0 + m0];
    const int HWm1 = (1 << g.log2HWout) - 1;
#pragma unroll
    for (int p = 0; p < PPT; ++p) {
        int nl = bit * PPB + part + p * TPS;
        f32x4 v = *(const f32x4*)&smf[nl][m0];
        f32x4 r;
        r.x = fmaxf((v.x - mean) * rstd * s4.x + b4.x, 0.f);
        r.y = fmaxf((v.y - mean) * rstd * s4.y + b4.y, 0.f);
        r.z = fmaxf((v.z - mean) * rstd * s4.z + b4.z, 0.f);
        r.w = fmaxf((v.w - mean) * rstd * s4.w + b4.w, 0.f);
        int n = ntile + nl;
        int ob = n >> g.log2HWout, opix = n & HWm1;
        long o = (((long)(g.b0o + ob) << g.log2HWout) + opix) * g.CTOT + C0 + m0;
        bf16x4 o4 = { (__bf16)r.x, (__bf16)r.y, (__bf16)r.z, (__bf16)r.w };
        *(bf16x4*)&out_[o] = o4;
    }
}

// ---------------- fat branch 1: g1 + d1 + m1 + specialized bulk pack ---------
#define B1_CONV 3072
#define B1_PACK 775
__global__ __launch_bounds__(512) void branch1_kern(
    const __bf16* __restrict__ geo_p, const __bf16* __restrict__ wg1, const float* __restrict__ g1_b, __bf16* __restrict__ g1out,
    const __bf16* __restrict__ dflow_pp, const __bf16* __restrict__ wd1, const float* __restrict__ d1_b, __bf16* __restrict__ d1out,
    const __bf16* __restrict__ mask_p, const __bf16* __restrict__ wm1, const float* __restrict__ m1_b, __bf16* __restrict__ m1out,
    BulkPack bp, ConvGeom gg1, ConvGeom gd1, ConvGeom gm1)
{
    __shared__ __attribute__((aligned(16))) char smem[27648];
    int x = blockIdx.x;
    if (x < 2048) {
        conv_dev<128, 128, 32, 512, 8, 3, 0, true, true>(smem, x, geo_p, wg1, g1_b, g1out, gg1);
        return;
    }
    if (x < 2560) {
        conv_dev<128, 128, 32, 512, 8, 7, 1, true, true>(smem, x - 2048, dflow_pp, wd1, d1_b, d1out, gd1);
        return;
    }
    if (x < B1_CONV) {
        conv_dev<64, 128, 64, 512, 8, 3, 0, true, true>(smem, x - 2560, mask_p, wm1, m1_b, m1out, gm1);
        return;
    }
    int x2 = x - B1_CONV;
    int tid = threadIdx.x;
    if (x2 < 18)       pack_conv8<64, 128, 1152>(bp.s[0], bp.d[0], x2 * 512 + tid);
    else if (x2 < 36)  pack_conv8<64, 128, 1152>(bp.s[1], bp.d[1], (x2 - 18) * 512 + tid);
    else if (x2 < 45)  pack_conv8<32, 64, 576>(bp.s[2], bp.d[2], (x2 - 36) * 512 + tid);
    else if (x2 < 127) pack_conv8<128, 288, 2624>(bp.s[3], bp.d[3], (x2 - 45) * 512 + tid);
    else if (x2 < 163) pack_conv8<128, 128, 1152>(bp.s[4], bp.d[4], (x2 - 127) * 512 + tid);
    else if (x2 < 199) pack_conv8<128, 128, 1152>(bp.s[5], bp.d[5], (x2 - 163) * 512 + tid);
    else if (x2 < 711) pack_fc1_8(bp.s[6], bp.d[6], (x2 - 199) * 512 + tid);
    else               pack_fc2_8(bp.s[7], bp.d[7], (x2 - 711) * 512 + tid);
}

// ---------------- fat branch 2: g2 + d2 + m2 (conv_dev3 dbuf) + hid ----------
// XCD-aware tile swizzle within each section (512 tiles): tiles with the same
// (bx&7) group land on one XCD (gcd(3,8)=1 preserves this under %3 interleave)
// -> adjacent n-tiles share tap-overlap rows in that XCD's L2.
#define B2_CONV 1536
#define B2_HID 4096
__global__ __launch_bounds__(256) void branch2_kern(
    const __bf16* __restrict__ g1out, const __bf16* __restrict__ wg2, const float* __restrict__ g2_b,
    const __bf16* __restrict__ d1out, const __bf16* __restrict__ wd2, const float* __restrict__ d2_b,
    const __bf16* __restrict__ m1out, const __bf16* __restrict__ wm2, const float* __restrict__ m2_b,
    const float* __restrict__ hidden, __bf16* __restrict__ enc, const __bf16* __restrict__ zpad,
    ConvGeom gg2, ConvGeom gd2, ConvGeom gm2)
{
    __shared__ __attribute__((aligned(16))) char smem[49152];  // 2 x (A 8KB + B 16KB)
    int x = blockIdx.x;
    if (x >= B2_CONV) { hid_dev(smem, hidden, enc, x - B2_CONV, threadIdx.x); return; }
    int sec = x % 3, bx = x / 3;
    bx = ((bx & 7) << 6) + (bx >> 3);   // bijective XCD swizzle over 512 tiles
    if (sec == 0)
        conv_dev3<128>(smem, bx, g1out, wg2, g2_b, enc, gg2, zpad);
    else if (sec == 1)
        conv_dev3<128>(smem, bx, d1out, wd2, d2_b, enc, gd2, zpad);
    else
        conv_dev3<64>(smem, bx, m1out, wm2, m2_b, enc, gm2, zpad);
}

// ---------------- fc1 split-K: grid (4 kchunks, 16 mtiles), atomic f32 ------
__global__ __launch_bounds__(256) void fc1_splitk(
    const __bf16* __restrict__ A, const __bf16* __restrict__ B,
    float* __restrict__ outacc)
{
    __shared__ __attribute__((aligned(16))) __bf16 As[64][40];
    __shared__ __attribute__((aligned(16))) __bf16 Bs[64][40];
    const int tid = threadIdx.x;
    const int mtile = blockIdx.y * 64;
    const int kbase = blockIdx.x * 512;
    const int lane = tid & 63, w = tid >> 6;
    const int wm = (w >> 1) * 32, wn = (w & 1) * 32;
    const int lr = lane & 15, lk = (lane >> 4) * 8;
    const int srow = tid >> 2, soff = (tid & 3) * 8;

    f32x4 acc00 = {}, acc01 = {}, acc10 = {}, acc11 = {};
    for (int k0 = 0; k0 < 512; k0 += 32) {
        *(bf16x8*)&As[srow][soff] = *(const bf16x8*)&A[(long)(mtile + srow) * 2048 + kbase + k0 + soff];
        *(bf16x8*)&Bs[srow][soff] = *(const bf16x8*)&B[(long)srow * 2048 + kbase + k0 + soff];
        __syncthreads();
        bf16x8 a0 = *(const bf16x8*)&As[wm + lr][lk];
        bf16x8 a1 = *(const bf16x8*)&As[wm + 16 + lr][lk];
        bf16x8 b0f = *(const bf16x8*)&Bs[wn + lr][lk];
        bf16x8 b1f = *(const bf16x8*)&Bs[wn + 16 + lr][lk];
        acc00 = __builtin_amdgcn_mfma_f32_16x16x32_bf16(a0, b0f, acc00, 0, 0, 0);
        acc01 = __builtin_amdgcn_mfma_f32_16x16x32_bf16(a0, b1f, acc01, 0, 0, 0);
        acc10 = __builtin_amdgcn_mfma_f32_16x16x32_bf16(a1, b0f, acc10, 0, 0, 0);
        acc11 = __builtin_amdgcn_mfma_f32_16x16x32_bf16(a1, b1f, acc11, 0, 0, 0);
        __syncthreads();
    }
    f32x4 accs[2][2] = { { acc00, acc01 }, { acc10, acc11 } };
#pragma unroll
    for (int mi = 0; mi < 2; ++mi) {
        int co0 = mtile + wm + mi * 16 + (lane >> 4) * 4;
#pragma unroll
        for (int ni = 0; ni < 2; ++ni) {
            int nn = wn + ni * 16 + lr;
            f32x4 v = accs[mi][ni];
            float* dst = &outacc[(long)nn * 1024 + co0];
            atomicAdd(dst + 0, v.x);
            atomicAdd(dst + 1, v.y);
            atomicAdd(dst + 2, v.z);
            atomicAdd(dst + 3, v.w);
        }
    }
}

// ---------------- fc2 split-K: B = relu(fc1acc + fc1_b) staged from f32 -----
__global__ __launch_bounds__(256) void fc2_splitk(
    const __bf16* __restrict__ A, const float* __restrict__ Bacc,
    const float* __restrict__ bb, float* __restrict__ outacc)
{
    __shared__ __attribute__((aligned(16))) __bf16 As[64][40];
    __shared__ __attribute__((aligned(16))) __bf16 Bs[64][40];
    const int tid = threadIdx.x;
    const int mtile = blockIdx.y * 64;
    const int kbase = blockIdx.x * 256;
    const int lane = tid & 63, w = tid >> 6;
    const int wm = (w >> 1) * 32, wn = (w & 1) * 32;
    const int lr = lane & 15, lk = (lane >> 4) * 8;
    const int srow = tid >> 2, soff = (tid & 3) * 8;

    f32x4 acc00 = {}, acc01 = {}, acc10 = {}, acc11 = {};
    for (int k0 = 0; k0 < 256; k0 += 32) {
        int k = kbase + k0 + soff;
        *(bf16x8*)&As[srow][soff] = *(const bf16x8*)&A[(long)(mtile + srow) * 1024 + k];
        f32x4 lo = *(const f32x4*)&Bacc[(long)srow * 1024 + k];
        f32x4 hi = *(const f32x4*)&Bacc[(long)srow * 1024 + k + 4];
        f32x4 blo = *(const f32x4*)&bb[k];
        f32x4 bhi = *(const f32x4*)&bb[k + 4];
        bf16x8 bvv;
        bvv[0] = (__bf16)fmaxf(lo.x + blo.x, 0.f);
        bvv[1] = (__bf16)fmaxf(lo.y + blo.y, 0.f);
        bvv[2] = (__bf16)fmaxf(lo.z + blo.z, 0.f);
        bvv[3] = (__bf16)fmaxf(lo.w + blo.w, 0.f);
        bvv[4] = (__bf16)fmaxf(hi.x + bhi.x, 0.f);
        bvv[5] = (__bf16)fmaxf(hi.y + bhi.y, 0.f);
        bvv[6] = (__bf16)fmaxf(hi.z + bhi.z, 0.f);
        bvv[7] = (__bf16)fmaxf(hi.w + bhi.w, 0.f);
        *(bf16x8*)&Bs[srow][soff] = bvv;
        __syncthreads();
        bf16x8 a0 = *(const bf16x8*)&As[wm + lr][lk];
        bf16x8 a1 = *(const bf16x8*)&As[wm + 16 + lr][lk];
        bf16x8 b0f = *(const bf16x8*)&Bs[wn + lr][lk];
        bf16x8 b1f = *(const bf16x8*)&Bs[wn + 16 + lr][lk];
        acc00 = __builtin_amdgcn_mfma_f32_16x16x32_bf16(a0, b0f, acc00, 0, 0, 0);
        acc01 = __builtin_amdgcn_mfma_f32_16x16x32_bf16(a0, b1f, acc01, 0, 0, 0);
        acc10 = __builtin_amdgcn_mfma_f32_16x16x32_bf16(a1, b0f, acc10, 0, 0, 0);
        acc11 = __builtin_amdgcn_mfma_f32_16x16x32_bf16(a1, b1f, acc11, 0, 0, 0);
        __syncthreads();
    }
    f32x4 accs[2][2] = { { acc00, acc01 }, { acc10, acc11 } };
#pragma unroll
    for (int mi = 0; mi < 2; ++mi) {
        int co0 = mtile + wm + mi * 16 + (lane >> 4) * 4;
#pragma unroll
        for (int ni = 0; ni < 2; ++ni) {
            int nn = wn + ni * 16 + lr;
            f32x4 v = accs[mi][ni];
            float* dst = &outacc[(long)nn * 256 + co0];
            atomicAdd(dst + 0, v.x);
            atomicAdd(dst + 1, v.y);
            atomicAdd(dst + 2, v.z);
            atomicAdd(dst + 3, v.w);
        }
    }
}

// ---------------- GroupNorm(32, cpg=4) NHWC f32 -> bf16 NHWC + relu ---------
__global__ void gn_nhwc(const float* __restrict__ in, const float* __restrict__ s,
                        const float* __restrict__ bi, __bf16* __restrict__ out,
                        int C, int HW)
{
    int b = blockIdx.x >> 5, g = blockIdx.x & 31;
    int tid = threadIdx.x, nt = blockDim.x;
    const float* p = in + (long)b * HW * C + g * 4;
    float sum = 0.f, sq = 0.f;
    for (int i = tid; i < HW; i += nt) {
        f32x4 v = *(const f32x4*)&p[(long)i * C];
        sum += v.x + v.y + v.z + v.w;
        sq  += v.x * v.x + v.y * v.y + v.z * v.z + v.w * v.w;
    }
    __shared__ float rs[256], rq[256];
    rs[tid] = sum; rq[tid] = sq; __syncthreads();
    for (int off = nt >> 1; off > 0; off >>= 1) {
        if (tid < off) { rs[tid] += rs[tid + off]; rq[tid] += rq[tid + off]; }
        __syncthreads();
    }
    int len = HW * 4;
    float mean = rs[0] / len;
    float var  = rq[0] / len - mean * mean;
    float rstd = rsqrtf(fmaxf(var, 0.f) + 1e-5f);
    f32x4 s4 = *(const f32x4*)&s[g * 4];
    f32x4 b4 = *(const f32x4*)&bi[g * 4];
    __bf16* q = out + (long)b * HW * C + g * 4;
    for (int i = tid; i < HW; i += nt) {
        f32x4 v = *(const f32x4*)&p[(long)i * C];
        f32x4 r;
        r.x = fmaxf((v.x - mean) * rstd * s4.x + b4.x, 0.f);
        r.y = fmaxf((v.y - mean) * rstd * s4.y + b4.y, 0.f);
        r.z = fmaxf((v.z - mean) * rstd * s4.z + b4.z, 0.f);
        r.w = fmaxf((v.w - mean) * rstd * s4.w + b4.w, 0.f);
        bf16x4 o4 = { (__bf16)r.x, (__bf16)r.y, (__bf16)r.z, (__bf16)r.w };
        *(bf16x4*)&q[(long)i * C] = o4;
    }
}

// ---------------- heads: wave-per-output, shuffle reduce ---------------------
__global__ __launch_bounds__(576) void head_kern(
    const float* __restrict__ x, const float* __restrict__ fb,
    const float* __restrict__ rw, const float* __restrict__ rb,
    const float* __restrict__ tw, const float* __restrict__ tb,
    const int* __restrict__ obj, float* __restrict__ out)
{
    int b = blockIdx.x;
    int k = threadIdx.x >> 6;        // 0..8
    int lane = threadIdx.x & 63;
    int j = obj[0] - 1;
    const float* xr = x + (long)b * 256;
    const float* wr;
    float bias0;
    if (k < 6) { wr = rw + (long)(j * 6 + k) * 256; bias0 = rb[j * 6 + k]; }
    else       { wr = tw + (long)(j * 3 + (k - 6)) * 256; bias0 = tb[j * 3 + (k - 6)]; }
    float acc = 0.f;
#pragma unroll
    for (int p = 0; p < 4; ++p) {
        int i = lane + p * 64;
        float xv = fmaxf(xr[i] + fb[i], 0.f);
        acc = fmaf(xv, wr[i], acc);
    }
#pragma unroll
    for (int off = 32; off > 0; off >>= 1) acc += __shfl_down(acc, off);
    if (lane == 0) {
        float r = acc + bias0;
        if (k < 6) out[b * 6 + k] = r;
        else       out[384 + b * 3 + (k - 6)] = r;
    }
}

extern "C" void kernel_launch(void* const* d_in, const int* in_sizes, int n_in,
                              void* d_out, int out_size, void* d_ws, size_t ws_size,
                              hipStream_t stream)
{
    const float* hidden = (const float*)d_in[0];
    const float* dflow  = (const float*)d_in[1];
    const float* mask   = (const float*)d_in[2];
    const float* geo    = (const float*)d_in[3];
    const int*   obj    = (const int*)d_in[4];
    const float* g1_w = (const float*)d_in[5],  *g1_b = (const float*)d_in[6];
    const float* g2_w = (const float*)d_in[7],  *g2_b = (const float*)d_in[8];
    const float* d1_w = (const float*)d_in[9],  *d1_b = (const float*)d_in[10];
    const float* d2_w = (const float*)d_in[11], *d2_b = (const float*)d_in[12];
    const float* m1_w = (const float*)d_in[13], *m1_b = (const float*)d_in[14];
    const float* m2_w = (const float*)d_in[15], *m2_b = (const float*)d_in[16];
    const float* c1_w = (const float*)d_in[17], *c1_b = (const float*)d_in[18];
    const float* gn1_s = (const float*)d_in[19], *gn1_bb = (const float*)d_in[20];
    const float* c2_w = (const float*)d_in[21], *c2_b = (const float*)d_in[22];
    const float* gn2_s = (const float*)d_in[23], *gn2_bb = (const float*)d_in[24];
    const float* c3_w = (const float*)d_in[25], *c3_b = (const float*)d_in[26];
    const float* gn3_s = (const float*)d_in[27], *gn3_bb = (const float*)d_in[28];
    const float* fc1_w = (const float*)d_in[29], *fc1_b = (const float*)d_in[30];
    const float* fc2_w = (const float*)d_in[31], *fc2_b = (const float*)d_in[32];
    const float* rot_w = (const float*)d_in[33], *rot_b = (const float*)d_in[34];
    const float* tr_w  = (const float*)d_in[35], *tr_b  = (const float*)d_in[36];

    char* ws = (char*)d_ws;
    __bf16* enc = (__bf16*)ws;                  // NHWC [64,32,32,288] = 37,748,736 B
    char* W = ws + 37748736;
    __bf16* wg1  = (__bf16*)(W + 0);            // [128][96]    24,576
    __bf16* wd1  = (__bf16*)(W + 24576);        // [128][128]   32,768 (mode 3)
    __bf16* wm1  = (__bf16*)(W + 57344);        // [64][128]    16,384
    __bf16* wg2  = (__bf16*)(W + 73728);        // [64][1152]  147,456
    __bf16* wd2  = (__bf16*)(W + 221184);       // [64][1152]  147,456
    __bf16* wm2  = (__bf16*)(W + 368640);       // [64][576]    73,728
    __bf16* wc1  = (__bf16*)(W + 442368);       // [128][2624] 671,744
    __bf16* wc2  = (__bf16*)(W + 1114112);      // [128][1152] 294,912
    __bf16* wc3  = (__bf16*)(W + 1409024);      // [128][1152] 294,912
    __bf16* wfc1 = (__bf16*)(W + 1703936);      // [1024][2048] 4,194,304
    __bf16* wfc2 = (__bf16*)(W + 5898240);      // [256][1024]  524,288
    // transients
    __bf16* geo_p    = (__bf16*)(ws + 44179456);   // [64,64,64,8]    4,194,304
    __bf16* dflow_pp = (__bf16*)(ws + 48373760);   // [64,40,40,2]      409,600
    __bf16* mask_p   = (__bf16*)(ws + 48783360);   // [64,32,32,8]    1,048,576
    __bf16* g1out    = (__bf16*)(ws + 49831936);   // [64,64,64,128] 67,108,864
    __bf16* d1out    = (__bf16*)(ws + 116940800);  // [64,32,32,128] 16,777,216
    __bf16* m1out    = (__bf16*)(ws + 133718016);  // [64,32,32,64]   8,388,608
    float*  c1raw    = (float*)(ws + 142106624);   // [64,16,16,128]  8,388,608
    __bf16* x1       = (__bf16*)(ws + 150495232);  //                 4,194,304
    __bf16* x2       = (__bf16*)(ws + 156786688);  // [64,8,8,128]    1,048,576
    __bf16* x3       = (__bf16*)(ws + 158359552);  // [64][2048]        262,144
    float*  fc1acc   = (float*)(ws + 158621696);   // [64][1024] f32    262,144
    float*  fc2acc   = (float*)(ws + 158883840);   // [64][256]  f32     65,536
    __bf16* zpad     = (__bf16*)(ws + 158949376);  // 4,096 B zero page (prep)

    // ---- PackArgs for prep (only sections 0..2 used: g1, d1, m1) ----
    PackArgs pa;
    {
        const float* srcs[11] = { g1_w, d1_w, m1_w, g2_w, d2_w, m2_w, c1_w, c2_w, c3_w, fc1_w, fc2_w };
        __bf16* dsts[11] = { wg1, wd1, wm1, wg2, wd2, wm2, wc1, wc2, wc3, wfc1, wfc2 };
        int Co[11]  = { 128, 128, 64, 64, 64, 32, 128, 128, 128, 1024, 256 };
        int Ci[11]  = { 8, 2, 1, 128, 128, 64, 288, 128, 128, 0, 0 };
        int KH[11]  = { 9, 49, 9, 9, 9, 9, 9, 9, 9, 0, 0 };
        int KWn[11] = { 3, 7, 3, 3, 3, 3, 3, 3, 3, 0, 0 };
        int Cp[11]  = { 8, 8, 8, 128, 128, 64, 288, 128, 128, 0, 0 };
        int Kp[11]  = { 96, 128, 128, 1152, 1152, 576, 2624, 1152, 1152, 2048, 1024 };
        int Mp[11]  = { 128, 128, 64, 64, 64, 64, 128, 128, 128, 1024, 256 };
        int Md[11]  = { 0, 3, 0, 0, 0, 0, 0, 0, 0, 1, 2 };
        int c = 0; pa.cum[0] = 0;
        for (int i = 0; i < 11; ++i) {
            pa.src[i] = srcs[i]; pa.dst[i] = dsts[i];
            pa.Cout[i] = Co[i]; pa.Cin[i] = Ci[i]; pa.KHW[i] = KH[i]; pa.KW[i] = KWn[i];
            pa.Cinpad[i] = Cp[i]; pa.Kpad[i] = Kp[i]; pa.mode[i] = Md[i];
            c += Mp[i] * Kp[i]; pa.cum[i + 1] = c;
        }
        // cum[3] == 36,864 == PACK_B*256
    }
    // ---- BulkPack for branch1 tail (sections 3..10) ----
    BulkPack bp;
    {
        const float* s[8] = { g2_w, d2_w, m2_w, c1_w, c2_w, c3_w, fc1_w, fc2_w };
        __bf16* d[8] = { wg2, wd2, wm2, wc1, wc2, wc3, wfc1, wfc2 };
        for (int i = 0; i < 8; ++i) { bp.s[i] = s[i]; bp.d[i] = d[i]; }
    }

    // ---- prep: b1 weight packs + vectorized pads + fc-acc/zpad zero ----
    {
        int total_blocks = PACK_B + GEOV_B + DF_B + MASKV_B + ZERO_B;  // 2,305
        prep_kern<<<dim3(total_blocks), 256, 0, stream>>>(pa, geo, geo_p, dflow, dflow_pp,
                                                          mask, mask_p, fc1acc, fc2acc);
    }

    // ConvGeom: CinTot,Hin,Win,log2HWout,log2Wout,stride,pad,Kpad,KHW,Cout,CTOT,C0,b0i,b0o
    // ---- branch stage 1: g1 + d1 + m1 + specialized bulk pack (512 thr) ----
    {
        ConvGeom gg1 = { 8, 64, 64, 12, 6, 1, 1, 96, 9, 128, 128, 0, 0, 0 };
        ConvGeom gd1 = { 2, 40, 40, 10, 5, 1, 0, 128, 49, 128, 128, 0, 0, 0 };
        ConvGeom gm1 = { 8, 32, 32, 10, 5, 1, 1, 128, 9, 64, 64, 0, 0, 0 };
        branch1_kern<<<dim3(B1_CONV + B1_PACK), 512, 0, stream>>>(geo_p, wg1, g1_b, g1out,
                                                                  dflow_pp, wd1, d1_b, d1out,
                                                                  mask_p, wm1, m1_b, m1out,
                                                                  bp, gg1, gd1, gm1);
    }
    // ---- branch stage 2: g2 + d2 + m2 (dbuf DMA + XCD swizzle) + hid ----
    {
        ConvGeom gg2 = { 128, 64, 64, 10, 5, 2, 1, 1152, 9, 64, 288, 224, 0, 0 };
        ConvGeom gd2 = { 128, 32, 32, 10, 5, 1, 1, 1152, 9, 64, 288, 128, 0, 0 };
        ConvGeom gm2 = { 64, 32, 32, 10, 5, 1, 1, 576, 9, 32, 288, 192, 0, 0 };
        branch2_kern<<<dim3(B2_CONV + B2_HID), 256, 0, stream>>>(g1out, wg2, g2_b,
                                                                 d1out, wd2, d2_b,
                                                                 m1out, wm2, m2_b,
                                                                 hidden, enc, zpad,
                                                                 gg2, gd2, gm2);
    }

    // ---- c1 + GN1 (BM=64 BN=128 wave 64x32, grid (128,2)) ----
    {
        ConvGeom gc1 = { 288, 32, 32, 8, 4, 2, 1, 2624, 9, 128, 128, 0, 0, 0 };
        conv_gemm2<64, 128, 64, 256, 1, 4, 288, 3, 0, false, false><<<dim3(128, 2), 256, 0, stream>>>(enc, wc1, c1_b, c1raw, gc1);
    }
    gn_nhwc<<<dim3(2048), 256, 0, stream>>>(c1raw, gn1_s, gn1_bb, x1, 128, 256);

    // ---- c2 fused GN2 (BN=64 = 1 batch x 64 px) ----
    {
        ConvGeom gc2 = { 128, 16, 16, 6, 3, 2, 1, 1152, 9, 128, 128, 0, 0, 0 };
        conv_gn_kern<64, 64, 64, 256, 2, 2, 128, 3, 64><<<dim3(64, 2), 256, 0, stream>>>(
            x1, wc2, c2_b, gn2_s, gn2_bb, x2, gc2);
    }
    // ---- c3 fused GN3 (BN=64 = 4 batches x 16 px) ----
    {
        ConvGeom gc3 = { 128, 8, 8, 4, 2, 2, 1, 1152, 9, 128, 128, 0, 0, 0 };
        conv_gn_kern<64, 64, 64, 256, 2, 2, 128, 3, 16><<<dim3(16, 2), 256, 0, stream>>>(
            x2, wc3, c3_b, gn3_s, gn3_bb, x3, gc3);
    }

    // ---- fc1 (split-K atomic), fc2 (split-K, B = relu(fc1acc+b)) ----
    fc1_splitk<<<dim3(4, 16), 256, 0, stream>>>(wfc1, x3, fc1acc);
    fc2_splitk<<<dim3(4, 4), 256, 0, stream>>>(wfc2, fc1acc, fc1_b, fc2acc);

    // ---- heads (applies fc2 bias + relu; 64 blocks x 9 waves) ----
    head_kern<<<dim3(64), 576, 0, stream>>>(fc2acc, fc2_b, rot_w, rot_b, tr_w, tr_b, obj, (float*)d_out);
}